// Round 3
// baseline (354.448 us; speedup 1.0000x reference)
//
#include <hip/hip_runtime.h>

#define H 320
#define W 320
#define HW (H * W)          // 102400
#define CH 64

typedef _Float16 f16;
typedef _Float16 f16x8 __attribute__((ext_vector_type(8)));
typedef float f32x16 __attribute__((ext_vector_type(16)));

// ---------------- bicubic x2 upsample (query 3x160x160 -> 3x320x320) --------
__device__ __forceinline__ float cubw(float t) {
    t = fabsf(t);
    if (t <= 1.f) return (1.25f * t - 2.25f) * t * t + 1.f;        // A=-0.75
    if (t < 2.f)  return -0.75f * (((t - 5.f) * t + 8.f) * t - 4.f);
    return 0.f;
}

__global__ __launch_bounds__(256) void bicubic_k(const float* __restrict__ q,
                                                 float* __restrict__ outp) {
    int idx = blockIdx.x * 256 + threadIdx.x;
    if (idx >= 3 * HW) return;
    int c = idx / HW;
    int r = idx - c * HW;
    int oy = r / W, ox = r - (r / W) * W;
    float sy = oy * 0.5f - 0.25f;
    float sx = ox * 0.5f - 0.25f;
    int iy0 = (int)floorf(sy);
    int ix0 = (int)floorf(sx);
    float wy[4], wx[4];
    int tyi[4], txi[4];
#pragma unroll
    for (int a = 0; a < 4; a++) {
        int ty = iy0 - 1 + a;
        wy[a] = cubw(sy - (float)ty);
        tyi[a] = min(max(ty, 0), 159);
        int tx = ix0 - 1 + a;
        wx[a] = cubw(sx - (float)tx);
        txi[a] = min(max(tx, 0), 159);
    }
    const float* ip = q + c * (160 * 160);
    float o = 0.f;
#pragma unroll
    for (int b = 0; b < 4; b++) {
        float s = 0.f;
#pragma unroll
        for (int a = 0; a < 4; a++) s += wy[a] * ip[tyi[a] * 160 + txi[b]];
        o += wx[b] * s;
    }
    outp[idx] = o;
}

// ---------------- direct 5x5 conv, CIN=3 (head conv1), out = NHWC f16 -------
// CIN=3 is MFMA-hostile (K=3/tap); keep the tuned direct kernel, emit NHWC f16.
__global__ __launch_bounds__(256, 3) void hconv_k(const float* __restrict__ in,
                                                  const float* __restrict__ wgt,
                                                  const float* __restrict__ bias,
                                                  f16* __restrict__ out) {
    constexpr int KS = 5, PAD = 2;
    constexpr int TWX = 36, TWY = 36, TSTR = 37;   // odd stride: bank-parity trick
    constexpr int KS2 = 25, WSTR = 28;
    constexpr int ICB = 3, OCB = 4;

    __shared__ float tile[ICB][TWY][TSTR];
    __shared__ float wl[ICB][OCB][WSTR];

    const int tid = threadIdx.x;
    const int tx = tid & 15, ty = tid >> 4;
    const int tileId = blockIdx.x >> 3;
    const int oc0 = (blockIdx.x & 7) * OCB;
    const int x0 = (tileId % 10) * 32;
    const int y0 = (tileId / 10) * 32;

    float acc[OCB][4];
#pragma unroll
    for (int i = 0; i < OCB; i++)
#pragma unroll
        for (int j = 0; j < 4; j++) acc[i][j] = 0.f;

    // stage input tile (+halo)
    for (int idx = tid; idx < ICB * TWY * TWX; idx += 256) {
        int icc = idx / (TWY * TWX);
        int rem = idx - icc * (TWY * TWX);
        int r = rem / TWX, c = rem - r * TWX;
        int iy = y0 - PAD + r;
        int ix = x0 - PAD + c;
        float v = 0.f;
        if (iy >= 0 && iy < H && ix >= 0 && ix < W)
            v = in[icc * HW + iy * W + ix];
        tile[icc][r][c] = v;
    }
    for (int idx = tid; idx < ICB * OCB * KS2; idx += 256) {
        int icc = idx / (OCB * KS2);
        int rem = idx - icc * (OCB * KS2);
        int oc = rem / KS2, t = rem - oc * KS2;
        wl[icc][oc][t] = wgt[((oc0 + oc) * ICB + icc) * KS2 + t];
    }
    __syncthreads();

#pragma unroll
    for (int icc = 0; icc < ICB; ++icc) {
        float win[2][KS][KS + 1];
#pragma unroll
        for (int h = 0; h < 2; h++)
#pragma unroll
            for (int r = 0; r < KS; r++)
#pragma unroll
                for (int c = 0; c < KS + 1; c++)
                    win[h][r][c] = tile[icc][ty + 16 * h + r][2 * tx + c];
#pragma unroll
        for (int oc = 0; oc < OCB; ++oc) {
            float wv[KS2];
#pragma unroll
            for (int t = 0; t < KS2; t++) wv[t] = wl[icc][oc][t];
#pragma unroll
            for (int h = 0; h < 2; h++)
#pragma unroll
                for (int r = 0; r < KS; r++)
#pragma unroll
                    for (int c = 0; c < KS; c++) {
                        acc[oc][2 * h]     += win[h][r][c]     * wv[r * KS + c];
                        acc[oc][2 * h + 1] += win[h][r][c + 1] * wv[r * KS + c];
                    }
        }
    }

    const int col = x0 + 2 * tx;
#pragma unroll
    for (int oc = 0; oc < OCB; ++oc) {
        float bv = bias[oc0 + oc];
#pragma unroll
        for (int h = 0; h < 2; h++) {
            int row = y0 + ty + 16 * h;
            int pix = row * W + col;
#pragma unroll
            for (int c2 = 0; c2 < 2; c2++) {
                float v = acc[oc][2 * h + c2] + bv;
                v = (v > 0.f) ? v : 0.2f * v;          // lrelu
                out[(pix + c2) * 32 + oc0 + oc] = (f16)v;
            }
        }
    }
}

// ---------------- weight repack: OIHW fp32 -> MFMA B-fragment order f16 -----
// Per layer, per (kc, tap), lane l holds B[k=8*(l>>5)+i][oc=l&31] as one f16x8.
// Layout: dst[base + ((kc*KS2 + t)*64 + l)*8 + i].
__global__ __launch_bounds__(256) void repack_k(const float* __restrict__ w0, // r1_w1
                                                const float* __restrict__ w1, // r1_w2
                                                const float* __restrict__ w2, // pr_w1
                                                const float* __restrict__ w3, // pr_w2
                                                const float* __restrict__ w4, // p1_w
                                                f16* __restrict__ dst) {
    int li = blockIdx.x * 256 + threadIdx.x;
    const float* src;
    int CIN, KS2, base, rel;
    if (li < 1152)       { src = w0; CIN = 32; KS2 = 9;  base = 0;     rel = li; }
    else if (li < 2304)  { src = w1; CIN = 32; KS2 = 9;  base = 9216;  rel = li - 1152; }
    else if (li < 3456)  { src = w2; CIN = 32; KS2 = 9;  base = 18432; rel = li - 2304; }
    else if (li < 4608)  { src = w3; CIN = 32; KS2 = 9;  base = 27648; rel = li - 3456; }
    else if (li < 11008) { src = w4; CIN = 64; KS2 = 25; base = 36864; rel = li - 4608; }
    else return;
    int fi = rel >> 6, l = rel & 63;
    int kc = fi / KS2, t = fi - kc * KS2;
    int oc = l & 31, kh = l >> 5;
#pragma unroll
    for (int i = 0; i < 8; ++i) {
        int ic = kc * 16 + kh * 8 + i;
        dst[base + rel * 8 + i] = (f16)src[(oc * CIN + ic) * KS2 + t];
    }
}

// ---------------- MFMA implicit-GEMM conv (NHWC f16 in/out, fp32 accum) -----
// Tap-decomposed GEMM on v_mfma_f32_32x32x16_f16:
//   D[pixel 0..31][oc 0..31] += A[pixel][k=ic16] * B[k][oc], per tap, per kc.
// Tile: 8 rows x 32 cols per block (400 blocks), wave w owns rows 2w,2w+1.
// A from LDS (NHWC tile + halo, staged once). LDS held as 8B units with
// XOR swizzle u^(p&(NU-1)): 64/128B pixel rows otherwise alias banks.
// Layouts (gfx950): D col=lane&31, row=(reg&3)+8*(reg>>2)+4*(lane>>5);
// A row=lane&31, k=8*(lane>>5)+i; B col=lane&31, k=8*(lane>>5)+i (repacked).
template <int KS, int CIN, int ACT, bool RES>
__global__ __launch_bounds__(256) void mconv_k(const f16* __restrict__ in,
                                               const f16* __restrict__ wrep,
                                               const float* __restrict__ bias,
                                               const f16* __restrict__ res,
                                               f16* __restrict__ out,
                                               int OUTC, int oc0) {
    constexpr int PAD = KS / 2;
    constexpr int TY = 8 + 2 * PAD;
    constexpr int TX = 32 + 2 * PAD;
    constexpr int NPX = TY * TX;
    constexpr int NU = CIN / 4;           // 8B units per pixel
    constexpr int UM = NU - 1;
    constexpr int KC = CIN / 16;
    constexpr int KS2 = KS * KS;

    __shared__ uint2 lds2[NPX * NU];      // 55.3 KB (CIN=64) / 21.8 KB (CIN=32)

    const int tid = threadIdx.x;
    const int bx = blockIdx.x % 10;
    const int by = blockIdx.x / 10;
    const int x0 = bx * 32, y0 = by * 8;

    // ---- stage NHWC tile (+halo), coalesced 8B loads, swizzled ds_writes ---
    {
        const int cu = tid & UM;
        constexpr int STEP = 256 / NU;    // 16 (CIN=64) or 32 (CIN=32)
        for (int p = tid / NU; p < NPX; p += STEP) {
            int ly = p / TX, lx = p - ly * TX;
            int gy = y0 - PAD + ly, gx = x0 - PAD + lx;
            uint2 v; v.x = 0u; v.y = 0u;
            if (gy >= 0 && gy < H && gx >= 0 && gx < W)
                v = *reinterpret_cast<const uint2*>(in + (gy * W + gx) * CIN + cu * 4);
            lds2[p * NU + (cu ^ (p & UM))] = v;
        }
    }
    __syncthreads();

    const int lane = tid & 63;
    const int wv = tid >> 6;              // wave 0..3
    const int R = lane & 31;              // A pixel-x / B,D oc column
    const int hh = lane >> 5;

    f32x16 acc0, acc1;
#pragma unroll
    for (int j = 0; j < 16; ++j) { acc0[j] = 0.f; acc1[j] = 0.f; }

#pragma unroll
    for (int kc = 0; kc < KC; ++kc) {
#pragma unroll
        for (int t = 0; t < KS2; ++t) {
            const int dy = t / KS, dx = t - dy * KS;
            f16x8 B = *reinterpret_cast<const f16x8*>(
                wrep + ((kc * KS2 + t) * 64 + lane) * 8);
            const int u0 = (kc * 2 + hh) * 2;
            {   // m = 0
                int p = (2 * wv + 0 + dy) * TX + R + dx;
                union { uint2 u[2]; f16x8 v; } A;
                A.u[0] = lds2[p * NU + ((u0)     ^ (p & UM))];
                A.u[1] = lds2[p * NU + ((u0 + 1) ^ (p & UM))];
                acc0 = __builtin_amdgcn_mfma_f32_32x32x16_f16(A.v, B, acc0, 0, 0, 0);
            }
            {   // m = 1
                int p = (2 * wv + 1 + dy) * TX + R + dx;
                union { uint2 u[2]; f16x8 v; } A;
                A.u[0] = lds2[p * NU + ((u0)     ^ (p & UM))];
                A.u[1] = lds2[p * NU + ((u0 + 1) ^ (p & UM))];
                acc1 = __builtin_amdgcn_mfma_f32_32x32x16_f16(A.v, B, acc1, 0, 0, 0);
            }
        }
    }

    // ---- epilogue: bias (+res) + activation, NHWC f16 stores ---------------
    const float bv = bias[R];
#pragma unroll
    for (int m = 0; m < 2; ++m) {
        const int gy = y0 + 2 * wv + m;
        f32x16 a = m ? acc1 : acc0;
#pragma unroll
        for (int r = 0; r < 16; ++r) {
            int X = x0 + (r & 3) + 8 * (r >> 2) + 4 * hh;
            int pix = gy * W + X;
            float v = a[r] + bv;
            if constexpr (RES) v += (float)res[pix * 32 + R];
            if constexpr (ACT == 0) v = fmaxf(v, 0.f);
            else                    v = (v > 0.f) ? v : 0.2f * v;
            out[pix * OUTC + oc0 + R] = (f16)v;
        }
    }
}

// ---------------- 1x1 conv 32->3 (NHWC f16 in), +1, clip --------------------
__global__ __launch_bounds__(256) void affine_k(const f16* __restrict__ hid,
                                                const float* __restrict__ w,
                                                const float* __restrict__ b,
                                                float* __restrict__ outp) {
    int p = blockIdx.x * 256 + threadIdx.x;
    if (p >= HW) return;
    const f16x8* hv = reinterpret_cast<const f16x8*>(hid + p * 32);
    float a0 = 0.f, a1 = 0.f, a2 = 0.f;
#pragma unroll
    for (int cc = 0; cc < 4; ++cc) {
        f16x8 hb = hv[cc];
#pragma unroll
        for (int j = 0; j < 8; ++j) {
            float hval = (float)hb[j];
            int c = cc * 8 + j;
            a0 += hval * w[c];
            a1 += hval * w[32 + c];
            a2 += hval * w[64 + c];
        }
    }
    a0 = fminf(fmaxf(a0 + b[0] + 1.f, -3.f), 3.f);
    a1 = fminf(fmaxf(a1 + b[1] + 1.f, -3.f), 3.f);
    a2 = fminf(fmaxf(a2 + b[2] + 1.f, -3.f), 3.f);
    outp[p] = a0;
    outp[HW + p] = a1;
    outp[2 * HW + p] = a2;
}

// ---------------- deformable 2x2 bilinear sampling --------------------------
// R3: latency + L2 restructure. Block = 128 ow x 2 oh (the kx row-pair) so
// both kx variants reuse the same x rows in-block; XCD-chunked block swizzle
// (1600 = 8*200, bijective) keeps neighboring h on the same L2; channel loop
// unrolled 8x for 32 gathers in flight; non-temporal streaming stores keep
// the 105 MB output from evicting x out of L2.
__device__ __forceinline__ int reflmap(int q) {
    int s = q - 1;
    if (s < 0) s = -s;
    else if (s > 319) s = 638 - s;
    return s;
}

__global__ __launch_bounds__(256) void sample_k(const float* __restrict__ x,
                                                const float* __restrict__ aff,
                                                float* __restrict__ outp) {
    int bid = blockIdx.x;                        // 1600 blocks
    bid = (bid & 7) * 200 + (bid >> 3);          // XCD-contiguous chunks
    const int h = bid / 5;                       // input row (0..319)
    const int q = bid - 5 * h;                   // 128-col quarter (0..4)
    const int tid = threadIdx.x;
    const int ow = q * 128 + (tid & 127);
    const int oh = 2 * h + (tid >> 7);

    const int w = ow >> 1;
    const int ky = ow & 1, kx = oh & 1;
    const int p = h * W + w;
    float s_x = aff[p];
    float s_y = aff[HW + p];
    float th = (aff[2 * HW + p] - 1.f) * 1.0472f;
    float pnx = kx ? 0.5f : -0.5f;
    float pny = ky ? 0.5f : -0.5f;
    float px = pnx * s_x, py = pny * s_y;
    float st, ct;
    __sincosf(th, &st, &ct);
    float rx = px * ct - py * st;
    float ry = px * st + py * ct;
    float p_x = rx + 0.5f + (float)(h + 1);
    float p_y = ry + 0.5f + (float)(w + 1);
    float ltx = floorf(p_x), lty = floorf(p_y);
    float rbx = ltx + 1.f, rby = lty + 1.f;
    float ltxc = fminf(fmaxf(ltx, 0.f), 321.f);
    float ltyc = fminf(fmaxf(lty, 0.f), 321.f);
    float rbxc = fminf(fmaxf(rbx, 0.f), 321.f);
    float rbyc = fminf(fmaxf(rby, 0.f), 321.f);
    p_x = fminf(fmaxf(p_x, 0.f), 321.f);
    p_y = fminf(fmaxf(p_y, 0.f), 321.f);
    float gx0 = 1.f + ltxc - p_x;
    float gx1 = 1.f - (rbxc - p_x);
    float gy0 = 1.f + ltyc - p_y;
    float gy1 = 1.f - (rbyc - p_y);
    float g_lt = gx0 * gy0, g_rb = gx1 * gy1, g_lb = gx0 * gy1, g_rt = gx1 * gy0;
    int ix0 = reflmap((int)ltxc), ix1 = reflmap((int)rbxc);
    int iy0 = reflmap((int)ltyc), iy1 = reflmap((int)rbyc);
    int o00 = ix0 * W + iy0;
    int o11 = ix1 * W + iy1;
    int o01 = ix0 * W + iy1;
    int o10 = ix1 * W + iy0;
    int obase = oh * 640 + ow;
#pragma unroll 8
    for (int c = 0; c < CH; c++) {
        const float* xc = x + c * HW;
        float v = g_lt * xc[o00] + g_rb * xc[o11] + g_lb * xc[o01] + g_rt * xc[o10];
        __builtin_nontemporal_store(v, outp + c * (640 * 640) + obase);
    }
}

// ---------------- launch ----------------------------------------------------
extern "C" void kernel_launch(void* const* d_in, const int* in_sizes, int n_in,
                              void* d_out, int out_size, void* d_ws, size_t ws_size,
                              hipStream_t stream) {
    const float* x       = (const float*)d_in[0];
    const float* query   = (const float*)d_in[1];
    const float* ref     = (const float*)d_in[2];
    const float* conv1_w = (const float*)d_in[3];
    const float* conv1_b = (const float*)d_in[4];
    const float* r1_w1   = (const float*)d_in[5];
    const float* r1_b1   = (const float*)d_in[6];
    const float* r1_w2   = (const float*)d_in[7];
    const float* r1_b2   = (const float*)d_in[8];
    const float* p1_w    = (const float*)d_in[9];
    const float* p1_b    = (const float*)d_in[10];
    const float* pr_w1   = (const float*)d_in[11];
    const float* pr_b1   = (const float*)d_in[12];
    const float* pr_w2   = (const float*)d_in[13];
    const float* pr_b2   = (const float*)d_in[14];
    const float* p2_w    = (const float*)d_in[15];
    const float* p2_b    = (const float*)d_in[16];

    float* outp = (float*)d_out;
    float* ws = (float*)d_ws;

    // ws (2.4 MB): fp32 qup + affine. d_out (104.8 MB) holds NHWC-f16
    // intermediates + repacked weights; all dead before sample_k rewrites it.
    float* qup    = ws;                       // 3*HW fp32
    float* affine = ws + 3 * HW;              // 3*HW fp32
    f16* feat = (f16*)outp;                   // [HW][64]  (rf ch 0..31, qf 32..63)
    f16* Bt   = (f16*)(outp + 32 * HW);       // [HW][32]
    f16* Ct   = (f16*)(outp + 48 * HW);       // [HW][32]
    f16* Dt   = (f16*)(outp + 64 * HW);       // [HW][32]
    f16* wrep = (f16*)(outp + 80 * HW);       // 88064 f16 repacked weights

    repack_k<<<43, 256, 0, stream>>>(r1_w1, r1_w2, pr_w1, pr_w2, p1_w, wrep);
    bicubic_k<<<1200, 256, 0, stream>>>(query, qup);

    // qf head
    hconv_k<<<800, 256, 0, stream>>>(qup, conv1_w, conv1_b, Bt);
    mconv_k<3, 32, 0, false><<<400, 256, 0, stream>>>(Bt, wrep,         r1_b1, nullptr, Ct, 32, 0);
    mconv_k<3, 32, 1, true ><<<400, 256, 0, stream>>>(Ct, wrep + 9216,  r1_b2, Bt, feat, 64, 32);

    // rf head
    hconv_k<<<800, 256, 0, stream>>>(ref, conv1_w, conv1_b, Bt);
    mconv_k<3, 32, 0, false><<<400, 256, 0, stream>>>(Bt, wrep,         r1_b1, nullptr, Ct, 32, 0);
    mconv_k<3, 32, 1, true ><<<400, 256, 0, stream>>>(Ct, wrep + 9216,  r1_b2, Bt, feat, 64, 0);

    // fusion head
    mconv_k<5, 64, 1, false><<<400, 256, 0, stream>>>(feat, wrep + 36864, p1_b, nullptr, Bt, 32, 0);
    mconv_k<3, 32, 0, false><<<400, 256, 0, stream>>>(Bt, wrep + 18432, pr_b1, nullptr, Ct, 32, 0);
    mconv_k<3, 32, 1, true ><<<400, 256, 0, stream>>>(Ct, wrep + 27648, pr_b2, Bt, Dt, 32, 0);

    affine_k<<<400, 256, 0, stream>>>(Dt, p2_w, p2_b, affine);

    sample_k<<<1600, 256, 0, stream>>>(x, affine, outp);
}

// Round 4
// 329.356 us; speedup vs baseline: 1.0762x; 1.0762x over previous
//
#include <hip/hip_runtime.h>

#define H 320
#define W 320
#define HW (H * W)          // 102400
#define CH 64

typedef _Float16 f16;
typedef _Float16 f16x8 __attribute__((ext_vector_type(8)));
typedef float f32x16 __attribute__((ext_vector_type(16)));

// ---------------- bicubic x2 upsample (query 3x160x160 -> 3x320x320) --------
__device__ __forceinline__ float cubw(float t) {
    t = fabsf(t);
    if (t <= 1.f) return (1.25f * t - 2.25f) * t * t + 1.f;        // A=-0.75
    if (t < 2.f)  return -0.75f * (((t - 5.f) * t + 8.f) * t - 4.f);
    return 0.f;
}

__global__ __launch_bounds__(256) void bicubic_k(const float* __restrict__ q,
                                                 float* __restrict__ outp) {
    int idx = blockIdx.x * 256 + threadIdx.x;
    if (idx >= 3 * HW) return;
    int c = idx / HW;
    int r = idx - c * HW;
    int oy = r / W, ox = r - (r / W) * W;
    float sy = oy * 0.5f - 0.25f;
    float sx = ox * 0.5f - 0.25f;
    int iy0 = (int)floorf(sy);
    int ix0 = (int)floorf(sx);
    float wy[4], wx[4];
    int tyi[4], txi[4];
#pragma unroll
    for (int a = 0; a < 4; a++) {
        int ty = iy0 - 1 + a;
        wy[a] = cubw(sy - (float)ty);
        tyi[a] = min(max(ty, 0), 159);
        int tx = ix0 - 1 + a;
        wx[a] = cubw(sx - (float)tx);
        txi[a] = min(max(tx, 0), 159);
    }
    const float* ip = q + c * (160 * 160);
    float o = 0.f;
#pragma unroll
    for (int b = 0; b < 4; b++) {
        float s = 0.f;
#pragma unroll
        for (int a = 0; a < 4; a++) s += wy[a] * ip[tyi[a] * 160 + txi[b]];
        o += wx[b] * s;
    }
    outp[idx] = o;
}

// ---------------- direct 5x5 conv, CIN=3, BATCH-2 (qup & ref), NHWC f16 -----
// blocks 0..799 -> in0 (qup), 800..1599 -> in1 (ref); out batch stride 32*HW.
__global__ __launch_bounds__(256, 3) void hconv_k(const float* __restrict__ in0,
                                                  const float* __restrict__ in1,
                                                  const float* __restrict__ wgt,
                                                  const float* __restrict__ bias,
                                                  f16* __restrict__ out) {
    constexpr int KS = 5, PAD = 2;
    constexpr int TWX = 36, TWY = 36, TSTR = 37;   // odd stride: bank-parity trick
    constexpr int KS2 = 25, WSTR = 28;
    constexpr int ICB = 3, OCB = 4;

    __shared__ float tile[ICB][TWY][TSTR];
    __shared__ float wl[ICB][OCB][WSTR];

    const int bb = blockIdx.x >= 800 ? 1 : 0;
    const int bid = blockIdx.x - bb * 800;
    const float* in = bb ? in1 : in0;
    f16* o = out + (size_t)bb * (32 * HW);

    const int tid = threadIdx.x;
    const int tx = tid & 15, ty = tid >> 4;
    const int tileId = bid >> 3;
    const int oc0 = (bid & 7) * OCB;
    const int x0 = (tileId % 10) * 32;
    const int y0 = (tileId / 10) * 32;

    float acc[OCB][4];
#pragma unroll
    for (int i = 0; i < OCB; i++)
#pragma unroll
        for (int j = 0; j < 4; j++) acc[i][j] = 0.f;

    // stage input tile (+halo)
    for (int idx = tid; idx < ICB * TWY * TWX; idx += 256) {
        int icc = idx / (TWY * TWX);
        int rem = idx - icc * (TWY * TWX);
        int r = rem / TWX, c = rem - r * TWX;
        int iy = y0 - PAD + r;
        int ix = x0 - PAD + c;
        float v = 0.f;
        if (iy >= 0 && iy < H && ix >= 0 && ix < W)
            v = in[icc * HW + iy * W + ix];
        tile[icc][r][c] = v;
    }
    for (int idx = tid; idx < ICB * OCB * KS2; idx += 256) {
        int icc = idx / (OCB * KS2);
        int rem = idx - icc * (OCB * KS2);
        int oc = rem / KS2, t = rem - oc * KS2;
        wl[icc][oc][t] = wgt[((oc0 + oc) * ICB + icc) * KS2 + t];
    }
    __syncthreads();

#pragma unroll
    for (int icc = 0; icc < ICB; ++icc) {
        float win[2][KS][KS + 1];
#pragma unroll
        for (int h = 0; h < 2; h++)
#pragma unroll
            for (int r = 0; r < KS; r++)
#pragma unroll
                for (int c = 0; c < KS + 1; c++)
                    win[h][r][c] = tile[icc][ty + 16 * h + r][2 * tx + c];
#pragma unroll
        for (int oc = 0; oc < OCB; ++oc) {
            float wv[KS2];
#pragma unroll
            for (int t = 0; t < KS2; t++) wv[t] = wl[icc][oc][t];
#pragma unroll
            for (int h = 0; h < 2; h++)
#pragma unroll
                for (int r = 0; r < KS; r++)
#pragma unroll
                    for (int c = 0; c < KS; c++) {
                        acc[oc][2 * h]     += win[h][r][c]     * wv[r * KS + c];
                        acc[oc][2 * h + 1] += win[h][r][c + 1] * wv[r * KS + c];
                    }
        }
    }

    const int col = x0 + 2 * tx;
#pragma unroll
    for (int oc = 0; oc < OCB; ++oc) {
        float bv = bias[oc0 + oc];
#pragma unroll
        for (int h = 0; h < 2; h++) {
            int row = y0 + ty + 16 * h;
            int pix = row * W + col;
#pragma unroll
            for (int c2 = 0; c2 < 2; c2++) {
                float v = acc[oc][2 * h + c2] + bv;
                v = (v > 0.f) ? v : 0.2f * v;          // lrelu
                o[(pix + c2) * 32 + oc0 + oc] = (f16)v;
            }
        }
    }
}

// ---------------- weight repack: OIHW fp32 -> MFMA B-fragment order f16 -----
// Per layer, per (kc, tap), lane l holds B[k=8*(l>>5)+i][oc=l&31] as one f16x8.
// Layout: dst[base + ((kc*KS2 + t)*64 + l)*8 + i].
__global__ __launch_bounds__(256) void repack_k(const float* __restrict__ w0, // r1_w1
                                                const float* __restrict__ w1, // r1_w2
                                                const float* __restrict__ w2, // pr_w1
                                                const float* __restrict__ w3, // pr_w2
                                                const float* __restrict__ w4, // p1_w
                                                f16* __restrict__ dst) {
    int li = blockIdx.x * 256 + threadIdx.x;
    const float* src;
    int CIN, KS2, base, rel;
    if (li < 1152)       { src = w0; CIN = 32; KS2 = 9;  base = 0;     rel = li; }
    else if (li < 2304)  { src = w1; CIN = 32; KS2 = 9;  base = 9216;  rel = li - 1152; }
    else if (li < 3456)  { src = w2; CIN = 32; KS2 = 9;  base = 18432; rel = li - 2304; }
    else if (li < 4608)  { src = w3; CIN = 32; KS2 = 9;  base = 27648; rel = li - 3456; }
    else if (li < 11008) { src = w4; CIN = 64; KS2 = 25; base = 36864; rel = li - 4608; }
    else return;
    int fi = rel >> 6, l = rel & 63;
    int kc = fi / KS2, t = fi - kc * KS2;
    int oc = l & 31, kh = l >> 5;
#pragma unroll
    for (int i = 0; i < 8; ++i) {
        int ic = kc * 16 + kh * 8 + i;
        dst[base + rel * 8 + i] = (f16)src[(oc * CIN + ic) * KS2 + t];
    }
}

// ---------------- MFMA implicit-GEMM conv (NHWC f16 in/out, fp32 accum) -----
// Tap-decomposed GEMM on v_mfma_f32_32x32x16_f16 (verified R2). Now batched:
// grid = batchN*400; b = blockIdx.x/400; pointers offset by b*{in,res,out}Str,
// oc0 = oc0Base + b*oc0Step. Inner loop untouched.
template <int KS, int CIN, int ACT, bool RES>
__global__ __launch_bounds__(256) void mconv_k(const f16* __restrict__ in,
                                               const f16* __restrict__ wrep,
                                               const float* __restrict__ bias,
                                               const f16* __restrict__ res,
                                               f16* __restrict__ out,
                                               int OUTC, int inStr, int resStr,
                                               int outStr, int oc0Base, int oc0Step) {
    constexpr int PAD = KS / 2;
    constexpr int TY = 8 + 2 * PAD;
    constexpr int TX = 32 + 2 * PAD;
    constexpr int NPX = TY * TX;
    constexpr int NU = CIN / 4;           // 8B units per pixel
    constexpr int UM = NU - 1;
    constexpr int KC = CIN / 16;
    constexpr int KS2 = KS * KS;

    __shared__ uint2 lds2[NPX * NU];      // 55.3 KB (CIN=64) / 21.8 KB (CIN=32)

    const int b = blockIdx.x >= 400 ? 1 : 0;
    const int tb = blockIdx.x - b * 400;
    in  += (size_t)b * inStr;
    res += (size_t)b * resStr;
    out += (size_t)b * outStr;
    const int oc0 = oc0Base + b * oc0Step;

    const int tid = threadIdx.x;
    const int bx = tb % 10;
    const int by = tb / 10;
    const int x0 = bx * 32, y0 = by * 8;

    // ---- stage NHWC tile (+halo), coalesced 8B loads, swizzled ds_writes ---
    {
        const int cu = tid & UM;
        constexpr int STEP = 256 / NU;    // 16 (CIN=64) or 32 (CIN=32)
        for (int p = tid / NU; p < NPX; p += STEP) {
            int ly = p / TX, lx = p - ly * TX;
            int gy = y0 - PAD + ly, gx = x0 - PAD + lx;
            uint2 v; v.x = 0u; v.y = 0u;
            if (gy >= 0 && gy < H && gx >= 0 && gx < W)
                v = *reinterpret_cast<const uint2*>(in + (gy * W + gx) * CIN + cu * 4);
            lds2[p * NU + (cu ^ (p & UM))] = v;
        }
    }
    __syncthreads();

    const int lane = tid & 63;
    const int wv = tid >> 6;              // wave 0..3
    const int R = lane & 31;              // A pixel-x / B,D oc column
    const int hh = lane >> 5;

    f32x16 acc0, acc1;
#pragma unroll
    for (int j = 0; j < 16; ++j) { acc0[j] = 0.f; acc1[j] = 0.f; }

#pragma unroll
    for (int kc = 0; kc < KC; ++kc) {
#pragma unroll
        for (int t = 0; t < KS2; ++t) {
            const int dy = t / KS, dx = t - dy * KS;
            f16x8 B = *reinterpret_cast<const f16x8*>(
                wrep + ((kc * KS2 + t) * 64 + lane) * 8);
            const int u0 = (kc * 2 + hh) * 2;
            {   // m = 0
                int p = (2 * wv + 0 + dy) * TX + R + dx;
                union { uint2 u[2]; f16x8 v; } A;
                A.u[0] = lds2[p * NU + ((u0)     ^ (p & UM))];
                A.u[1] = lds2[p * NU + ((u0 + 1) ^ (p & UM))];
                acc0 = __builtin_amdgcn_mfma_f32_32x32x16_f16(A.v, B, acc0, 0, 0, 0);
            }
            {   // m = 1
                int p = (2 * wv + 1 + dy) * TX + R + dx;
                union { uint2 u[2]; f16x8 v; } A;
                A.u[0] = lds2[p * NU + ((u0)     ^ (p & UM))];
                A.u[1] = lds2[p * NU + ((u0 + 1) ^ (p & UM))];
                acc1 = __builtin_amdgcn_mfma_f32_32x32x16_f16(A.v, B, acc1, 0, 0, 0);
            }
        }
    }

    // ---- epilogue: bias (+res) + activation, NHWC f16 stores ---------------
    const float bv = bias[R];
#pragma unroll
    for (int m = 0; m < 2; ++m) {
        const int gy = y0 + 2 * wv + m;
        f32x16 a = m ? acc1 : acc0;
#pragma unroll
        for (int r = 0; r < 16; ++r) {
            int X = x0 + (r & 3) + 8 * (r >> 2) + 4 * hh;
            int pix = gy * W + X;
            float v = a[r] + bv;
            if constexpr (RES) v += (float)res[pix * 32 + R];
            if constexpr (ACT == 0) v = fmaxf(v, 0.f);
            else                    v = (v > 0.f) ? v : 0.2f * v;
            out[pix * OUTC + oc0 + R] = (f16)v;
        }
    }
}

// ---------------- 1x1 conv 32->3 (NHWC f16 in), +1, clip --------------------
__global__ __launch_bounds__(256) void affine_k(const f16* __restrict__ hid,
                                                const float* __restrict__ w,
                                                const float* __restrict__ b,
                                                float* __restrict__ outp) {
    int p = blockIdx.x * 256 + threadIdx.x;
    if (p >= HW) return;
    const f16x8* hv = reinterpret_cast<const f16x8*>(hid + p * 32);
    float a0 = 0.f, a1 = 0.f, a2 = 0.f;
#pragma unroll
    for (int cc = 0; cc < 4; ++cc) {
        f16x8 hb = hv[cc];
#pragma unroll
        for (int j = 0; j < 8; ++j) {
            float hval = (float)hb[j];
            int c = cc * 8 + j;
            a0 += hval * w[c];
            a1 += hval * w[32 + c];
            a2 += hval * w[64 + c];
        }
    }
    a0 = fminf(fmaxf(a0 + b[0] + 1.f, -3.f), 3.f);
    a1 = fminf(fmaxf(a1 + b[1] + 1.f, -3.f), 3.f);
    a2 = fminf(fmaxf(a2 + b[2] + 1.f, -3.f), 3.f);
    outp[p] = a0;
    outp[HW + p] = a1;
    outp[2 * HW + p] = a2;
}

// ---------------- deformable 2x2 bilinear sampling --------------------------
// R4: the gathers were TA-transaction-bound (R2 vs R3: FETCH 70->14 MB, dur
// unchanged). Stage the provably-sufficient x window (rows h-2..h+3, cols
// w0-4..w0+67, incl. reflection) into LDS in two 32-channel chunks (55.3 KB,
// 2 blocks/CU) with coalesced float4 loads (each line fetched once), then the
// 4 bilinear taps are ds_read_b32. Writes stay nontemporal streaming.
__device__ __forceinline__ int reflmap(int q) {
    int s = q - 1;
    if (s < 0) s = -s;
    else if (s > 319) s = 638 - s;
    return s;
}

__global__ __launch_bounds__(256) void sample_k(const float* __restrict__ x,
                                                const float* __restrict__ aff,
                                                float* __restrict__ outp) {
    __shared__ float tile[32 * 6 * 72];          // 55.3 KB
    int bid = blockIdx.x;                        // 1600 blocks
    bid = (bid & 7) * 200 + (bid >> 3);          // XCD-contiguous chunks
    const int h = bid / 5;                       // input row (0..319)
    const int q = bid - 5 * h;                   // 128-col quarter (0..4)
    const int tid = threadIdx.x;
    const int ow = q * 128 + (tid & 127);
    const int oh = 2 * h + (tid >> 7);

    const int w = ow >> 1;
    const int ky = ow & 1, kx = oh & 1;
    const int p = h * W + w;
    float s_x = aff[p];
    float s_y = aff[HW + p];
    float th = (aff[2 * HW + p] - 1.f) * 1.0472f;
    float pnx = kx ? 0.5f : -0.5f;
    float pny = ky ? 0.5f : -0.5f;
    float px = pnx * s_x, py = pny * s_y;
    float st, ct;
    __sincosf(th, &st, &ct);
    float rx = px * ct - py * st;
    float ry = px * st + py * ct;
    float p_x = rx + 0.5f + (float)(h + 1);
    float p_y = ry + 0.5f + (float)(w + 1);
    float ltx = floorf(p_x), lty = floorf(p_y);
    float rbx = ltx + 1.f, rby = lty + 1.f;
    float ltxc = fminf(fmaxf(ltx, 0.f), 321.f);
    float ltyc = fminf(fmaxf(lty, 0.f), 321.f);
    float rbxc = fminf(fmaxf(rbx, 0.f), 321.f);
    float rbyc = fminf(fmaxf(rby, 0.f), 321.f);
    p_x = fminf(fmaxf(p_x, 0.f), 321.f);
    p_y = fminf(fmaxf(p_y, 0.f), 321.f);
    float gx0 = 1.f + ltxc - p_x;
    float gx1 = 1.f - (rbxc - p_x);
    float gy0 = 1.f + ltyc - p_y;
    float gy1 = 1.f - (rbyc - p_y);
    float g_lt = gx0 * gy0, g_rb = gx1 * gy1, g_lb = gx0 * gy1, g_rt = gx1 * gy0;
    int ix0 = reflmap((int)ltxc), ix1 = reflmap((int)rbxc);
    int iy0 = reflmap((int)ltyc), iy1 = reflmap((int)rbyc);

    // LDS word offsets within the staged [6][72] window (proven in-range:
    // ix in [max(0,h-2), min(319,h+3)], iy in [w0-2, w0+66]).
    const int rowbase = h - 2;
    const int colbase = q * 64 - 4;
    const int o00 = (ix0 - rowbase) * 72 + (iy0 - colbase);
    const int o01 = (ix0 - rowbase) * 72 + (iy1 - colbase);
    const int o10 = (ix1 - rowbase) * 72 + (iy0 - colbase);
    const int o11 = (ix1 - rowbase) * 72 + (iy1 - colbase);
    const int obase = oh * 640 + ow;

    for (int half = 0; half < 2; ++half) {
        const int ch0 = half * 32;
        __syncthreads();                         // protect prior-chunk reads
        // stage 32 ch x 6 rows x 72 cols, float4-coalesced, zero-guarded
        for (int idx = tid; idx < 3456; idx += 256) {
            int ch = idx / 108;
            int rem = idx - ch * 108;
            int row = rem / 18;
            int g = rem - row * 18;
            int rv = rowbase + row;
            int cv = colbase + 4 * g;            // 4-aligned; fully in/out of range
            float4 v = make_float4(0.f, 0.f, 0.f, 0.f);
            if (rv >= 0 && rv < H && cv >= 0 && cv < W)
                v = *reinterpret_cast<const float4*>(x + (size_t)(ch0 + ch) * HW + rv * W + cv);
            *reinterpret_cast<float4*>(&tile[ch * 432 + row * 72 + 4 * g]) = v;
        }
        __syncthreads();
#pragma unroll 8
        for (int c = 0; c < 32; ++c) {
            const float* t = tile + c * 432;
            float v = g_lt * t[o00] + g_rb * t[o11] + g_lb * t[o01] + g_rt * t[o10];
            __builtin_nontemporal_store(v, outp + (size_t)(ch0 + c) * (640 * 640) + obase);
        }
    }
}

// ---------------- launch ----------------------------------------------------
extern "C" void kernel_launch(void* const* d_in, const int* in_sizes, int n_in,
                              void* d_out, int out_size, void* d_ws, size_t ws_size,
                              hipStream_t stream) {
    const float* x       = (const float*)d_in[0];
    const float* query   = (const float*)d_in[1];
    const float* ref     = (const float*)d_in[2];
    const float* conv1_w = (const float*)d_in[3];
    const float* conv1_b = (const float*)d_in[4];
    const float* r1_w1   = (const float*)d_in[5];
    const float* r1_b1   = (const float*)d_in[6];
    const float* r1_w2   = (const float*)d_in[7];
    const float* r1_b2   = (const float*)d_in[8];
    const float* p1_w    = (const float*)d_in[9];
    const float* p1_b    = (const float*)d_in[10];
    const float* pr_w1   = (const float*)d_in[11];
    const float* pr_b1   = (const float*)d_in[12];
    const float* pr_w2   = (const float*)d_in[13];
    const float* pr_b2   = (const float*)d_in[14];
    const float* p2_w    = (const float*)d_in[15];
    const float* p2_b    = (const float*)d_in[16];

    float* outp = (float*)d_out;
    float* ws = (float*)d_ws;

    // ws (2.4 MB): fp32 qup + affine. d_out (104.8 MB) holds NHWC-f16
    // intermediates + repacked weights; all dead before sample_k rewrites it.
    float* qup    = ws;                        // 3*HW fp32
    float* affine = ws + 3 * HW;               // 3*HW fp32
    f16* feat = (f16*)outp;                    // [HW][64] (rf ch 0..31, qf 32..63)
    f16* Bt   = (f16*)(outp + 32 * HW);        // [2][HW][32] batch: 0=q, 1=ref
    f16* Ct   = (f16*)(outp + 64 * HW);        // [2][HW][32]
    f16* Dt   = (f16*)(outp + 96 * HW);        // [HW][32]
    f16* wrep = (f16*)(outp + 112 * HW);       // 88064 f16 repacked weights

    repack_k<<<43, 256, 0, stream>>>(r1_w1, r1_w2, pr_w1, pr_w2, p1_w, wrep);
    bicubic_k<<<1200, 256, 0, stream>>>(query, qup);

    // both heads, batch-2 (batch0 = qf from qup, batch1 = rf from ref)
    hconv_k<<<1600, 256, 0, stream>>>(qup, ref, conv1_w, conv1_b, Bt);
    mconv_k<3, 32, 0, false><<<800, 256, 0, stream>>>(Bt, wrep,        r1_b1, nullptr, Ct,
                                                      32, 32 * HW, 0, 32 * HW, 0, 0);
    mconv_k<3, 32, 1, true ><<<800, 256, 0, stream>>>(Ct, wrep + 9216, r1_b2, Bt, feat,
                                                      64, 32 * HW, 32 * HW, 0, 32, -32);

    // fusion head (single batch)
    mconv_k<5, 64, 1, false><<<400, 256, 0, stream>>>(feat, wrep + 36864, p1_b, nullptr, Bt,
                                                      32, 0, 0, 0, 0, 0);
    mconv_k<3, 32, 0, false><<<400, 256, 0, stream>>>(Bt, wrep + 18432, pr_b1, nullptr, Ct,
                                                      32, 0, 0, 0, 0, 0);
    mconv_k<3, 32, 1, true ><<<400, 256, 0, stream>>>(Ct, wrep + 27648, pr_b2, Bt, Dt,
                                                      32, 0, 0, 0, 0, 0);

    affine_k<<<400, 256, 0, stream>>>(Dt, p2_w, p2_b, affine);

    sample_k<<<1600, 256, 0, stream>>>(x, affine, outp);
}

// Round 5
// 308.414 us; speedup vs baseline: 1.1493x; 1.0679x over previous
//
#include <hip/hip_runtime.h>

#define H 320
#define W 320
#define HW (H * W)          // 102400
#define CH 64

typedef _Float16 f16;
typedef _Float16 f16x8 __attribute__((ext_vector_type(8)));
typedef float f32x16 __attribute__((ext_vector_type(16)));

// ---------------- bicubic x2 upsample (query 3x160x160 -> 3x320x320) --------
__device__ __forceinline__ float cubw(float t) {
    t = fabsf(t);
    if (t <= 1.f) return (1.25f * t - 2.25f) * t * t + 1.f;        // A=-0.75
    if (t < 2.f)  return -0.75f * (((t - 5.f) * t + 8.f) * t - 4.f);
    return 0.f;
}

__global__ __launch_bounds__(256) void bicubic_k(const float* __restrict__ q,
                                                 float* __restrict__ outp) {
    int idx = blockIdx.x * 256 + threadIdx.x;
    if (idx >= 3 * HW) return;
    int c = idx / HW;
    int r = idx - c * HW;
    int oy = r / W, ox = r - (r / W) * W;
    float sy = oy * 0.5f - 0.25f;
    float sx = ox * 0.5f - 0.25f;
    int iy0 = (int)floorf(sy);
    int ix0 = (int)floorf(sx);
    float wy[4], wx[4];
    int tyi[4], txi[4];
#pragma unroll
    for (int a = 0; a < 4; a++) {
        int ty = iy0 - 1 + a;
        wy[a] = cubw(sy - (float)ty);
        tyi[a] = min(max(ty, 0), 159);
        int tx = ix0 - 1 + a;
        wx[a] = cubw(sx - (float)tx);
        txi[a] = min(max(tx, 0), 159);
    }
    const float* ip = q + c * (160 * 160);
    float o = 0.f;
#pragma unroll
    for (int b = 0; b < 4; b++) {
        float s = 0.f;
#pragma unroll
        for (int a = 0; a < 4; a++) s += wy[a] * ip[tyi[a] * 160 + txi[b]];
        o += wx[b] * s;
    }
    outp[idx] = o;
}

// ---------------- direct 5x5 conv, CIN=3, BATCH-2 (qup & ref), NHWC f16 -----
// blocks 0..799 -> in0 (qup), 800..1599 -> in1 (ref); out batch stride 32*HW.
__global__ __launch_bounds__(256, 3) void hconv_k(const float* __restrict__ in0,
                                                  const float* __restrict__ in1,
                                                  const float* __restrict__ wgt,
                                                  const float* __restrict__ bias,
                                                  f16* __restrict__ out) {
    constexpr int KS = 5, PAD = 2;
    constexpr int TWX = 36, TWY = 36, TSTR = 37;   // odd stride: bank-parity trick
    constexpr int KS2 = 25, WSTR = 28;
    constexpr int ICB = 3, OCB = 4;

    __shared__ float tile[ICB][TWY][TSTR];
    __shared__ float wl[ICB][OCB][WSTR];

    const int bb = blockIdx.x >= 800 ? 1 : 0;
    const int bid = blockIdx.x - bb * 800;
    const float* in = bb ? in1 : in0;
    f16* o = out + (size_t)bb * (32 * HW);

    const int tid = threadIdx.x;
    const int tx = tid & 15, ty = tid >> 4;
    const int tileId = bid >> 3;
    const int oc0 = (bid & 7) * OCB;
    const int x0 = (tileId % 10) * 32;
    const int y0 = (tileId / 10) * 32;

    float acc[OCB][4];
#pragma unroll
    for (int i = 0; i < OCB; i++)
#pragma unroll
        for (int j = 0; j < 4; j++) acc[i][j] = 0.f;

    // stage input tile (+halo)
    for (int idx = tid; idx < ICB * TWY * TWX; idx += 256) {
        int icc = idx / (TWY * TWX);
        int rem = idx - icc * (TWY * TWX);
        int r = rem / TWX, c = rem - r * TWX;
        int iy = y0 - PAD + r;
        int ix = x0 - PAD + c;
        float v = 0.f;
        if (iy >= 0 && iy < H && ix >= 0 && ix < W)
            v = in[icc * HW + iy * W + ix];
        tile[icc][r][c] = v;
    }
    for (int idx = tid; idx < ICB * OCB * KS2; idx += 256) {
        int icc = idx / (OCB * KS2);
        int rem = idx - icc * (OCB * KS2);
        int oc = rem / KS2, t = rem - oc * KS2;
        wl[icc][oc][t] = wgt[((oc0 + oc) * ICB + icc) * KS2 + t];
    }
    __syncthreads();

#pragma unroll
    for (int icc = 0; icc < ICB; ++icc) {
        float win[2][KS][KS + 1];
#pragma unroll
        for (int h = 0; h < 2; h++)
#pragma unroll
            for (int r = 0; r < KS; r++)
#pragma unroll
                for (int c = 0; c < KS + 1; c++)
                    win[h][r][c] = tile[icc][ty + 16 * h + r][2 * tx + c];
#pragma unroll
        for (int oc = 0; oc < OCB; ++oc) {
            float wv[KS2];
#pragma unroll
            for (int t = 0; t < KS2; t++) wv[t] = wl[icc][oc][t];
#pragma unroll
            for (int h = 0; h < 2; h++)
#pragma unroll
                for (int r = 0; r < KS; r++)
#pragma unroll
                    for (int c = 0; c < KS; c++) {
                        acc[oc][2 * h]     += win[h][r][c]     * wv[r * KS + c];
                        acc[oc][2 * h + 1] += win[h][r][c + 1] * wv[r * KS + c];
                    }
        }
    }

    const int col = x0 + 2 * tx;
#pragma unroll
    for (int oc = 0; oc < OCB; ++oc) {
        float bv = bias[oc0 + oc];
#pragma unroll
        for (int h = 0; h < 2; h++) {
            int row = y0 + ty + 16 * h;
            int pix = row * W + col;
#pragma unroll
            for (int c2 = 0; c2 < 2; c2++) {
                float v = acc[oc][2 * h + c2] + bv;
                v = (v > 0.f) ? v : 0.2f * v;          // lrelu
                o[(pix + c2) * 32 + oc0 + oc] = (f16)v;
            }
        }
    }
}

// ---------------- weight repack: OIHW fp32 -> MFMA B-fragment order f16 -----
// Per layer, per (kc, tap), lane l holds B[k=8*(l>>5)+i][oc=l&31] as one f16x8.
// Layout: dst[base + ((kc*KS2 + t)*64 + l)*8 + i].
__global__ __launch_bounds__(256) void repack_k(const float* __restrict__ w0, // r1_w1
                                                const float* __restrict__ w1, // r1_w2
                                                const float* __restrict__ w2, // pr_w1
                                                const float* __restrict__ w3, // pr_w2
                                                const float* __restrict__ w4, // p1_w
                                                f16* __restrict__ dst) {
    int li = blockIdx.x * 256 + threadIdx.x;
    const float* src;
    int CIN, KS2, base, rel;
    if (li < 1152)       { src = w0; CIN = 32; KS2 = 9;  base = 0;     rel = li; }
    else if (li < 2304)  { src = w1; CIN = 32; KS2 = 9;  base = 9216;  rel = li - 1152; }
    else if (li < 3456)  { src = w2; CIN = 32; KS2 = 9;  base = 18432; rel = li - 2304; }
    else if (li < 4608)  { src = w3; CIN = 32; KS2 = 9;  base = 27648; rel = li - 3456; }
    else if (li < 11008) { src = w4; CIN = 64; KS2 = 25; base = 36864; rel = li - 4608; }
    else return;
    int fi = rel >> 6, l = rel & 63;
    int kc = fi / KS2, t = fi - kc * KS2;
    int oc = l & 31, kh = l >> 5;
#pragma unroll
    for (int i = 0; i < 8; ++i) {
        int ic = kc * 16 + kh * 8 + i;
        dst[base + rel * 8 + i] = (f16)src[(oc * CIN + ic) * KS2 + t];
    }
}

// ---------------- MFMA implicit-GEMM conv (NHWC f16 in/out, fp32 accum) -----
// Tap-decomposed GEMM on v_mfma_f32_32x32x16_f16 (verified R2). Batched:
// grid = batchN*400; b = blockIdx.x/400; pointers offset by b*{in,res,out}Str,
// oc0 = oc0Base + b*oc0Step. Inner loop untouched.
template <int KS, int CIN, int ACT, bool RES>
__global__ __launch_bounds__(256) void mconv_k(const f16* __restrict__ in,
                                               const f16* __restrict__ wrep,
                                               const float* __restrict__ bias,
                                               const f16* __restrict__ res,
                                               f16* __restrict__ out,
                                               int OUTC, int inStr, int resStr,
                                               int outStr, int oc0Base, int oc0Step) {
    constexpr int PAD = KS / 2;
    constexpr int TY = 8 + 2 * PAD;
    constexpr int TX = 32 + 2 * PAD;
    constexpr int NPX = TY * TX;
    constexpr int NU = CIN / 4;           // 8B units per pixel
    constexpr int UM = NU - 1;
    constexpr int KC = CIN / 16;
    constexpr int KS2 = KS * KS;

    __shared__ uint2 lds2[NPX * NU];      // 55.3 KB (CIN=64) / 21.8 KB (CIN=32)

    const int b = blockIdx.x >= 400 ? 1 : 0;
    const int tb = blockIdx.x - b * 400;
    in  += (size_t)b * inStr;
    res += (size_t)b * resStr;
    out += (size_t)b * outStr;
    const int oc0 = oc0Base + b * oc0Step;

    const int tid = threadIdx.x;
    const int bx = tb % 10;
    const int by = tb / 10;
    const int x0 = bx * 32, y0 = by * 8;

    // ---- stage NHWC tile (+halo), coalesced 8B loads, swizzled ds_writes ---
    {
        const int cu = tid & UM;
        constexpr int STEP = 256 / NU;    // 16 (CIN=64) or 32 (CIN=32)
        for (int p = tid / NU; p < NPX; p += STEP) {
            int ly = p / TX, lx = p - ly * TX;
            int gy = y0 - PAD + ly, gx = x0 - PAD + lx;
            uint2 v; v.x = 0u; v.y = 0u;
            if (gy >= 0 && gy < H && gx >= 0 && gx < W)
                v = *reinterpret_cast<const uint2*>(in + (gy * W + gx) * CIN + cu * 4);
            lds2[p * NU + (cu ^ (p & UM))] = v;
        }
    }
    __syncthreads();

    const int lane = tid & 63;
    const int wv = tid >> 6;              // wave 0..3
    const int R = lane & 31;              // A pixel-x / B,D oc column
    const int hh = lane >> 5;

    f32x16 acc0, acc1;
#pragma unroll
    for (int j = 0; j < 16; ++j) { acc0[j] = 0.f; acc1[j] = 0.f; }

#pragma unroll
    for (int kc = 0; kc < KC; ++kc) {
#pragma unroll
        for (int t = 0; t < KS2; ++t) {
            const int dy = t / KS, dx = t - dy * KS;
            f16x8 B = *reinterpret_cast<const f16x8*>(
                wrep + ((kc * KS2 + t) * 64 + lane) * 8);
            const int u0 = (kc * 2 + hh) * 2;
            {   // m = 0
                int p = (2 * wv + 0 + dy) * TX + R + dx;
                union { uint2 u[2]; f16x8 v; } A;
                A.u[0] = lds2[p * NU + ((u0)     ^ (p & UM))];
                A.u[1] = lds2[p * NU + ((u0 + 1) ^ (p & UM))];
                acc0 = __builtin_amdgcn_mfma_f32_32x32x16_f16(A.v, B, acc0, 0, 0, 0);
            }
            {   // m = 1
                int p = (2 * wv + 1 + dy) * TX + R + dx;
                union { uint2 u[2]; f16x8 v; } A;
                A.u[0] = lds2[p * NU + ((u0)     ^ (p & UM))];
                A.u[1] = lds2[p * NU + ((u0 + 1) ^ (p & UM))];
                acc1 = __builtin_amdgcn_mfma_f32_32x32x16_f16(A.v, B, acc1, 0, 0, 0);
            }
        }
    }

    // ---- epilogue: bias (+res) + activation, NHWC f16 stores ---------------
    const float bv = bias[R];
#pragma unroll
    for (int m = 0; m < 2; ++m) {
        const int gy = y0 + 2 * wv + m;
        f32x16 a = m ? acc1 : acc0;
#pragma unroll
        for (int r = 0; r < 16; ++r) {
            int X = x0 + (r & 3) + 8 * (r >> 2) + 4 * hh;
            int pix = gy * W + X;
            float v = a[r] + bv;
            if constexpr (RES) v += (float)res[pix * 32 + R];
            if constexpr (ACT == 0) v = fmaxf(v, 0.f);
            else                    v = (v > 0.f) ? v : 0.2f * v;
            out[pix * OUTC + oc0 + R] = (f16)v;
        }
    }
}

// ---------------- 1x1 conv 32->3 (NHWC f16 in), +1, clip --------------------
__global__ __launch_bounds__(256) void affine_k(const f16* __restrict__ hid,
                                                const float* __restrict__ w,
                                                const float* __restrict__ b,
                                                float* __restrict__ outp) {
    int p = blockIdx.x * 256 + threadIdx.x;
    if (p >= HW) return;
    const f16x8* hv = reinterpret_cast<const f16x8*>(hid + p * 32);
    float a0 = 0.f, a1 = 0.f, a2 = 0.f;
#pragma unroll
    for (int cc = 0; cc < 4; ++cc) {
        f16x8 hb = hv[cc];
#pragma unroll
        for (int j = 0; j < 8; ++j) {
            float hval = (float)hb[j];
            int c = cc * 8 + j;
            a0 += hval * w[c];
            a1 += hval * w[32 + c];
            a2 += hval * w[64 + c];
        }
    }
    a0 = fminf(fmaxf(a0 + b[0] + 1.f, -3.f), 3.f);
    a1 = fminf(fmaxf(a1 + b[1] + 1.f, -3.f), 3.f);
    a2 = fminf(fmaxf(a2 + b[2] + 1.f, -3.f), 3.f);
    outp[p] = a0;
    outp[HW + p] = a1;
    outp[2 * HW + p] = a2;
}

// ---------------- deformable 2x2 bilinear sampling --------------------------
// R5: occupancy + bank-geometry fix. R4 counters: 55.3 KB LDS -> 2 blocks/CU
// (18.5% occ) serialized stage/read phases; [6][72] stride put jittered rows
// 8 banks apart (3.26M conflicts). Now: block = 16 ch x (h, 128-col quarter),
// LDS 16x6x96 fp32 = 36.9 KB -> 4 blocks/CU, grid 6400, ONE barrier. Row
// stride 96 (and ch stride 576) are bank-neutral (mult of 32): bank = iy%32
// only -> <=2 lanes/bank = free. Words 72..95/row are an unread pad.
__device__ __forceinline__ int reflmap(int q) {
    int s = q - 1;
    if (s < 0) s = -s;
    else if (s > 319) s = 638 - s;
    return s;
}

__global__ __launch_bounds__(256) void sample_k(const float* __restrict__ x,
                                                const float* __restrict__ aff,
                                                float* __restrict__ outp) {
    __shared__ float tile[16 * 6 * 96];          // 36.9 KB
    int bid = blockIdx.x;                        // 6400 = 4 ch-groups x 1600 tiles
    bid = (bid & 7) * 800 + (bid >> 3);          // XCD-contiguous chunks
    const int cg = bid / 1600;                   // 16-channel group
    const int tb = bid - cg * 1600;
    const int h = tb / 5;                        // input row (0..319)
    const int q = tb - 5 * h;                    // 128-col quarter (0..4)
    const int tid = threadIdx.x;
    const int ow = q * 128 + (tid & 127);
    const int oh = 2 * h + (tid >> 7);

    const int w = ow >> 1;
    const int ky = ow & 1, kx = oh & 1;
    const int p = h * W + w;
    float s_x = aff[p];
    float s_y = aff[HW + p];
    float th = (aff[2 * HW + p] - 1.f) * 1.0472f;
    float pnx = kx ? 0.5f : -0.5f;
    float pny = ky ? 0.5f : -0.5f;
    float px = pnx * s_x, py = pny * s_y;
    float st, ct;
    __sincosf(th, &st, &ct);
    float rx = px * ct - py * st;
    float ry = px * st + py * ct;
    float p_x = rx + 0.5f + (float)(h + 1);
    float p_y = ry + 0.5f + (float)(w + 1);
    float ltx = floorf(p_x), lty = floorf(p_y);
    float rbx = ltx + 1.f, rby = lty + 1.f;
    float ltxc = fminf(fmaxf(ltx, 0.f), 321.f);
    float ltyc = fminf(fmaxf(lty, 0.f), 321.f);
    float rbxc = fminf(fmaxf(rbx, 0.f), 321.f);
    float rbyc = fminf(fmaxf(rby, 0.f), 321.f);
    p_x = fminf(fmaxf(p_x, 0.f), 321.f);
    p_y = fminf(fmaxf(p_y, 0.f), 321.f);
    float gx0 = 1.f + ltxc - p_x;
    float gx1 = 1.f - (rbxc - p_x);
    float gy0 = 1.f + ltyc - p_y;
    float gy1 = 1.f - (rbyc - p_y);
    float g_lt = gx0 * gy0, g_rb = gx1 * gy1, g_lb = gx0 * gy1, g_rt = gx1 * gy0;
    int ix0 = reflmap((int)ltxc), ix1 = reflmap((int)rbxc);
    int iy0 = reflmap((int)ltyc), iy1 = reflmap((int)rbyc);

    // LDS word offsets within the staged [6][96-padded] window (in-range
    // proof: ix in [max(0,h-2), min(319,h+3)], iy-colbase in [2, 71]).
    const int rowbase = h - 2;
    const int colbase = q * 64 - 4;
    const int o00 = (ix0 - rowbase) * 96 + (iy0 - colbase);
    const int o01 = (ix0 - rowbase) * 96 + (iy1 - colbase);
    const int o10 = (ix1 - rowbase) * 96 + (iy0 - colbase);
    const int o11 = (ix1 - rowbase) * 96 + (iy1 - colbase);
    const int obase = oh * 640 + ow;
    const int ch0 = cg * 16;

    // stage 16 ch x 6 rows x 18 float4 (72 valid words/row), zero-guarded
    for (int idx = tid; idx < 1728; idx += 256) {
        int ch = idx / 108;
        int rem = idx - ch * 108;
        int row = rem / 18;
        int g = rem - row * 18;
        int rv = rowbase + row;
        int cv = colbase + 4 * g;                // 4-aligned
        float4 v = make_float4(0.f, 0.f, 0.f, 0.f);
        if (rv >= 0 && rv < H && cv >= 0 && cv < W)
            v = *reinterpret_cast<const float4*>(x + (size_t)(ch0 + ch) * HW + rv * W + cv);
        *reinterpret_cast<float4*>(&tile[ch * 576 + row * 96 + 4 * g]) = v;
    }
    __syncthreads();

#pragma unroll
    for (int c = 0; c < 16; ++c) {
        const float* t = tile + c * 576;
        float v = g_lt * t[o00] + g_rb * t[o11] + g_lb * t[o01] + g_rt * t[o10];
        __builtin_nontemporal_store(v, outp + (size_t)(ch0 + c) * (640 * 640) + obase);
    }
}

// ---------------- launch ----------------------------------------------------
extern "C" void kernel_launch(void* const* d_in, const int* in_sizes, int n_in,
                              void* d_out, int out_size, void* d_ws, size_t ws_size,
                              hipStream_t stream) {
    const float* x       = (const float*)d_in[0];
    const float* query   = (const float*)d_in[1];
    const float* ref     = (const float*)d_in[2];
    const float* conv1_w = (const float*)d_in[3];
    const float* conv1_b = (const float*)d_in[4];
    const float* r1_w1   = (const float*)d_in[5];
    const float* r1_b1   = (const float*)d_in[6];
    const float* r1_w2   = (const float*)d_in[7];
    const float* r1_b2   = (const float*)d_in[8];
    const float* p1_w    = (const float*)d_in[9];
    const float* p1_b    = (const float*)d_in[10];
    const float* pr_w1   = (const float*)d_in[11];
    const float* pr_b1   = (const float*)d_in[12];
    const float* pr_w2   = (const float*)d_in[13];
    const float* pr_b2   = (const float*)d_in[14];
    const float* p2_w    = (const float*)d_in[15];
    const float* p2_b    = (const float*)d_in[16];

    float* outp = (float*)d_out;
    float* ws = (float*)d_ws;

    // ws (2.4 MB): fp32 qup + affine. d_out (104.8 MB) holds NHWC-f16
    // intermediates + repacked weights; all dead before sample_k rewrites it.
    float* qup    = ws;                        // 3*HW fp32
    float* affine = ws + 3 * HW;               // 3*HW fp32
    f16* feat = (f16*)outp;                    // [HW][64] (rf ch 0..31, qf 32..63)
    f16* Bt   = (f16*)(outp + 32 * HW);        // [2][HW][32] batch: 0=q, 1=ref
    f16* Ct   = (f16*)(outp + 64 * HW);        // [2][HW][32]
    f16* Dt   = (f16*)(outp + 96 * HW);        // [HW][32]
    f16* wrep = (f16*)(outp + 112 * HW);       // 88064 f16 repacked weights

    repack_k<<<43, 256, 0, stream>>>(r1_w1, r1_w2, pr_w1, pr_w2, p1_w, wrep);
    bicubic_k<<<1200, 256, 0, stream>>>(query, qup);

    // both heads, batch-2 (batch0 = qf from qup, batch1 = rf from ref)
    hconv_k<<<1600, 256, 0, stream>>>(qup, ref, conv1_w, conv1_b, Bt);
    mconv_k<3, 32, 0, false><<<800, 256, 0, stream>>>(Bt, wrep,        r1_b1, nullptr, Ct,
                                                      32, 32 * HW, 0, 32 * HW, 0, 0);
    mconv_k<3, 32, 1, true ><<<800, 256, 0, stream>>>(Ct, wrep + 9216, r1_b2, Bt, feat,
                                                      64, 32 * HW, 32 * HW, 0, 32, -32);

    // fusion head (single batch)
    mconv_k<5, 64, 1, false><<<400, 256, 0, stream>>>(feat, wrep + 36864, p1_b, nullptr, Bt,
                                                      32, 0, 0, 0, 0, 0);
    mconv_k<3, 32, 0, false><<<400, 256, 0, stream>>>(Bt, wrep + 18432, pr_b1, nullptr, Ct,
                                                      32, 0, 0, 0, 0, 0);
    mconv_k<3, 32, 1, true ><<<400, 256, 0, stream>>>(Ct, wrep + 27648, pr_b2, Bt, Dt,
                                                      32, 0, 0, 0, 0, 0);

    affine_k<<<400, 256, 0, stream>>>(Dt, p2_w, p2_b, affine);

    sample_k<<<6400, 256, 0, stream>>>(x, affine, outp);
}

// Round 6
// 273.439 us; speedup vs baseline: 1.2963x; 1.1279x over previous
//
#include <hip/hip_runtime.h>

#define H 320
#define W 320
#define HW (H * W)          // 102400
#define CH 64

typedef _Float16 f16;
typedef _Float16 f16x8 __attribute__((ext_vector_type(8)));
typedef float f32x16 __attribute__((ext_vector_type(16)));

// ---------------- bicubic x2 upsample (query 3x160x160 -> 3x320x320) --------
__device__ __forceinline__ float cubw(float t) {
    t = fabsf(t);
    if (t <= 1.f) return (1.25f * t - 2.25f) * t * t + 1.f;        // A=-0.75
    if (t < 2.f)  return -0.75f * (((t - 5.f) * t + 8.f) * t - 4.f);
    return 0.f;
}

__global__ __launch_bounds__(256) void bicubic_k(const float* __restrict__ q,
                                                 float* __restrict__ outp) {
    int idx = blockIdx.x * 256 + threadIdx.x;
    if (idx >= 3 * HW) return;
    int c = idx / HW;
    int r = idx - c * HW;
    int oy = r / W, ox = r - (r / W) * W;
    float sy = oy * 0.5f - 0.25f;
    float sx = ox * 0.5f - 0.25f;
    int iy0 = (int)floorf(sy);
    int ix0 = (int)floorf(sx);
    float wy[4], wx[4];
    int tyi[4], txi[4];
#pragma unroll
    for (int a = 0; a < 4; a++) {
        int ty = iy0 - 1 + a;
        wy[a] = cubw(sy - (float)ty);
        tyi[a] = min(max(ty, 0), 159);
        int tx = ix0 - 1 + a;
        wx[a] = cubw(sx - (float)tx);
        txi[a] = min(max(tx, 0), 159);
    }
    const float* ip = q + c * (160 * 160);
    float o = 0.f;
#pragma unroll
    for (int b = 0; b < 4; b++) {
        float s = 0.f;
#pragma unroll
        for (int a = 0; a < 4; a++) s += wy[a] * ip[tyi[a] * 160 + txi[b]];
        o += wx[b] * s;
    }
    outp[idx] = o;
}

// ---------------- weight repack: OIHW fp32 -> MFMA B-fragment order f16 -----
// Generic layers: per (kc, tap), lane l holds B[k=8*(l>>5)+i][oc=l&31].
// conv1 (li in [11008,11328)): tap-folded im2col K=80 (k = tap*3+ic, k>=75 -> 0).
__global__ __launch_bounds__(256) void repack_k(const float* __restrict__ w0, // r1_w1
                                                const float* __restrict__ w1, // r1_w2
                                                const float* __restrict__ w2, // pr_w1
                                                const float* __restrict__ w3, // pr_w2
                                                const float* __restrict__ w4, // p1_w
                                                const float* __restrict__ w5, // conv1_w
                                                f16* __restrict__ dst) {
    int li = blockIdx.x * 256 + threadIdx.x;
    if (li >= 11328) return;
    if (li >= 11008) {   // conv1: K=80 tap-folded, base 88064
        int rel = li - 11008;
        int kc = rel >> 6, l = rel & 63;
        int oc = l & 31, kh = l >> 5;
#pragma unroll
        for (int i = 0; i < 8; ++i) {
            int k = kc * 16 + kh * 8 + i;
            f16 v = (f16)0.f;
            if (k < 75) {
                int tap = k / 3, ic = k - 3 * tap;      // tap = ky*5+kx
                v = (f16)w5[(oc * 3 + ic) * 25 + tap];
            }
            dst[88064 + rel * 8 + i] = v;
        }
        return;
    }
    const float* src;
    int CIN, KS2, base, rel;
    if (li < 1152)       { src = w0; CIN = 32; KS2 = 9;  base = 0;     rel = li; }
    else if (li < 2304)  { src = w1; CIN = 32; KS2 = 9;  base = 9216;  rel = li - 1152; }
    else if (li < 3456)  { src = w2; CIN = 32; KS2 = 9;  base = 18432; rel = li - 2304; }
    else if (li < 4608)  { src = w3; CIN = 32; KS2 = 9;  base = 27648; rel = li - 3456; }
    else                 { src = w4; CIN = 64; KS2 = 25; base = 36864; rel = li - 4608; }
    int fi = rel >> 6, l = rel & 63;
    int kc = fi / KS2, t = fi - kc * KS2;
    int oc = l & 31, kh = l >> 5;
#pragma unroll
    for (int i = 0; i < 8; ++i) {
        int ic = kc * 16 + kh * 8 + i;
        dst[base + rel * 8 + i] = (f16)src[(oc * CIN + ic) * KS2 + t];
    }
}

// ---------------- conv1 via MFMA, tap-folded im2col (CIN=3, 5x5) ------------
// R6: replaces the VALU-direct hconv_k (~1200 fp32 FMA/thread, ~2700 cyc/wave)
// with 10 MFMA + 80 ds_read_b32/wave (~700 cyc). K = 25 taps x 3 ic = 75,
// padded to 80 = 5 chunks of 16. fp32 tile in LDS (5.8 KB), A gathered
// per-element + cvt to f16; each half-wave reads 32 consecutive words ->
// conflict-free. Batch-2: blocks 0..399 -> in0 (qup), 400..799 -> in1 (ref).
__global__ __launch_bounds__(256) void hconv_m(const float* __restrict__ in0,
                                               const float* __restrict__ in1,
                                               const f16* __restrict__ wr5,
                                               const float* __restrict__ bias,
                                               f16* __restrict__ out) {
    __shared__ float tile[3][12][40];        // rows y0-2..y0+9, cols x0-2..x0+37
    const int b = blockIdx.x >= 400 ? 1 : 0;
    const int tb = blockIdx.x - b * 400;
    const float* in = b ? in1 : in0;
    f16* o = out + (size_t)b * (32 * HW);
    const int x0 = (tb % 10) * 32, y0 = (tb / 10) * 8;
    const int tid = threadIdx.x;

    for (int idx = tid; idx < 1440; idx += 256) {
        int ic = idx / 480;
        int rem = idx - ic * 480;
        int r = rem / 40, c = rem - r * 40;
        int gy = y0 - 2 + r, gx = x0 - 2 + c;
        float v = 0.f;
        if (gy >= 0 && gy < H && gx >= 0 && gx < W)
            v = in[ic * HW + gy * W + gx];
        tile[ic][r][c] = v;
    }
    __syncthreads();

    const int lane = tid & 63, wv = tid >> 6;
    const int R = lane & 31, hh = lane >> 5;

    f32x16 acc0, acc1;
#pragma unroll
    for (int j = 0; j < 16; ++j) { acc0[j] = 0.f; acc1[j] = 0.f; }

#pragma unroll
    for (int kc = 0; kc < 5; ++kc) {
        f16x8 B = *reinterpret_cast<const f16x8*>(wr5 + (kc * 64 + lane) * 8);
#pragma unroll
        for (int m = 0; m < 2; ++m) {
            f16x8 A;
#pragma unroll
            for (int i = 0; i < 8; ++i) {
                int k = kc * 16 + hh * 8 + i;
                float v = 0.f;
                if (k < 75) {
                    int tap = k / 3, ic = k - 3 * tap;
                    int dy = tap / 5, dx = tap - 5 * dy;
                    v = tile[ic][2 * wv + m + dy][R + dx];
                }
                A[i] = (f16)v;
            }
            if (m == 0) acc0 = __builtin_amdgcn_mfma_f32_32x32x16_f16(A, B, acc0, 0, 0, 0);
            else        acc1 = __builtin_amdgcn_mfma_f32_32x32x16_f16(A, B, acc1, 0, 0, 0);
        }
    }

    const float bv = bias[R];
#pragma unroll
    for (int m = 0; m < 2; ++m) {
        const int gy = y0 + 2 * wv + m;
        f32x16 a = m ? acc1 : acc0;
#pragma unroll
        for (int r = 0; r < 16; ++r) {
            int X = x0 + (r & 3) + 8 * (r >> 2) + 4 * hh;
            float v = a[r] + bv;
            v = (v > 0.f) ? v : 0.2f * v;              // lrelu
            o[(gy * W + X) * 32 + R] = (f16)v;
        }
    }
}

// ---------------- MFMA implicit-GEMM conv (NHWC f16 in/out, fp32 accum) -----
// Tap-decomposed GEMM on v_mfma_f32_32x32x16_f16 (verified R2). Batched:
// grid = batchN*400; b = blockIdx.x/400; pointers offset by b*{in,res,out}Str,
// oc0 = oc0Base + b*oc0Step. Inner loop untouched.
template <int KS, int CIN, int ACT, bool RES>
__global__ __launch_bounds__(256) void mconv_k(const f16* __restrict__ in,
                                               const f16* __restrict__ wrep,
                                               const float* __restrict__ bias,
                                               const f16* __restrict__ res,
                                               f16* __restrict__ out,
                                               int OUTC, int inStr, int resStr,
                                               int outStr, int oc0Base, int oc0Step) {
    constexpr int PAD = KS / 2;
    constexpr int TY = 8 + 2 * PAD;
    constexpr int TX = 32 + 2 * PAD;
    constexpr int NPX = TY * TX;
    constexpr int NU = CIN / 4;           // 8B units per pixel
    constexpr int UM = NU - 1;
    constexpr int KC = CIN / 16;
    constexpr int KS2 = KS * KS;

    __shared__ uint2 lds2[NPX * NU];      // 55.3 KB (CIN=64) / 21.8 KB (CIN=32)

    const int b = blockIdx.x >= 400 ? 1 : 0;
    const int tb = blockIdx.x - b * 400;
    in  += (size_t)b * inStr;
    res += (size_t)b * resStr;
    out += (size_t)b * outStr;
    const int oc0 = oc0Base + b * oc0Step;

    const int tid = threadIdx.x;
    const int bx = tb % 10;
    const int by = tb / 10;
    const int x0 = bx * 32, y0 = by * 8;

    // ---- stage NHWC tile (+halo), coalesced 8B loads, swizzled ds_writes ---
    {
        const int cu = tid & UM;
        constexpr int STEP = 256 / NU;    // 16 (CIN=64) or 32 (CIN=32)
        for (int p = tid / NU; p < NPX; p += STEP) {
            int ly = p / TX, lx = p - ly * TX;
            int gy = y0 - PAD + ly, gx = x0 - PAD + lx;
            uint2 v; v.x = 0u; v.y = 0u;
            if (gy >= 0 && gy < H && gx >= 0 && gx < W)
                v = *reinterpret_cast<const uint2*>(in + (gy * W + gx) * CIN + cu * 4);
            lds2[p * NU + (cu ^ (p & UM))] = v;
        }
    }
    __syncthreads();

    const int lane = tid & 63;
    const int wv = tid >> 6;              // wave 0..3
    const int R = lane & 31;              // A pixel-x / B,D oc column
    const int hh = lane >> 5;

    f32x16 acc0, acc1;
#pragma unroll
    for (int j = 0; j < 16; ++j) { acc0[j] = 0.f; acc1[j] = 0.f; }

#pragma unroll
    for (int kc = 0; kc < KC; ++kc) {
#pragma unroll
        for (int t = 0; t < KS2; ++t) {
            const int dy = t / KS, dx = t - dy * KS;
            f16x8 B = *reinterpret_cast<const f16x8*>(
                wrep + ((kc * KS2 + t) * 64 + lane) * 8);
            const int u0 = (kc * 2 + hh) * 2;
            {   // m = 0
                int p = (2 * wv + 0 + dy) * TX + R + dx;
                union { uint2 u[2]; f16x8 v; } A;
                A.u[0] = lds2[p * NU + ((u0)     ^ (p & UM))];
                A.u[1] = lds2[p * NU + ((u0 + 1) ^ (p & UM))];
                acc0 = __builtin_amdgcn_mfma_f32_32x32x16_f16(A.v, B, acc0, 0, 0, 0);
            }
            {   // m = 1
                int p = (2 * wv + 1 + dy) * TX + R + dx;
                union { uint2 u[2]; f16x8 v; } A;
                A.u[0] = lds2[p * NU + ((u0)     ^ (p & UM))];
                A.u[1] = lds2[p * NU + ((u0 + 1) ^ (p & UM))];
                acc1 = __builtin_amdgcn_mfma_f32_32x32x16_f16(A.v, B, acc1, 0, 0, 0);
            }
        }
    }

    // ---- epilogue: bias (+res) + activation, NHWC f16 stores ---------------
    const float bv = bias[R];
#pragma unroll
    for (int m = 0; m < 2; ++m) {
        const int gy = y0 + 2 * wv + m;
        f32x16 a = m ? acc1 : acc0;
#pragma unroll
        for (int r = 0; r < 16; ++r) {
            int X = x0 + (r & 3) + 8 * (r >> 2) + 4 * hh;
            int pix = gy * W + X;
            float v = a[r] + bv;
            if constexpr (RES) v += (float)res[pix * 32 + R];
            if constexpr (ACT == 0) v = fmaxf(v, 0.f);
            else                    v = (v > 0.f) ? v : 0.2f * v;
            out[pix * OUTC + oc0 + R] = (f16)v;
        }
    }
}

// ---------------- 1x1 conv 32->3 (NHWC f16 in), +1, clip --------------------
__global__ __launch_bounds__(256) void affine_k(const f16* __restrict__ hid,
                                                const float* __restrict__ w,
                                                const float* __restrict__ b,
                                                float* __restrict__ outp) {
    int p = blockIdx.x * 256 + threadIdx.x;
    if (p >= HW) return;
    const f16x8* hv = reinterpret_cast<const f16x8*>(hid + p * 32);
    float a0 = 0.f, a1 = 0.f, a2 = 0.f;
#pragma unroll
    for (int cc = 0; cc < 4; ++cc) {
        f16x8 hb = hv[cc];
#pragma unroll
        for (int j = 0; j < 8; ++j) {
            float hval = (float)hb[j];
            int c = cc * 8 + j;
            a0 += hval * w[c];
            a1 += hval * w[32 + c];
            a2 += hval * w[64 + c];
        }
    }
    a0 = fminf(fmaxf(a0 + b[0] + 1.f, -3.f), 3.f);
    a1 = fminf(fmaxf(a1 + b[1] + 1.f, -3.f), 3.f);
    a2 = fminf(fmaxf(a2 + b[2] + 1.f, -3.f), 3.f);
    outp[p] = a0;
    outp[HW + p] = a1;
    outp[2 * HW + p] = a2;
}

// ---------------- deformable 2x2 bilinear sampling --------------------------
// R6: row stride 96 -> 80 (LDS 30.7 KB -> 5 blocks/CU, 20 waves) for more
// phase overlap. 80%32=16: row-parity shifts banks by 16; with ~32-consecutive
// per-lane cols the read stays <=2-3 lanes/bank. Pad words 72..79 unread.
__device__ __forceinline__ int reflmap(int q) {
    int s = q - 1;
    if (s < 0) s = -s;
    else if (s > 319) s = 638 - s;
    return s;
}

__global__ __launch_bounds__(256) void sample_k(const float* __restrict__ x,
                                                const float* __restrict__ aff,
                                                float* __restrict__ outp) {
    __shared__ float tile[16 * 6 * 80];          // 30.7 KB
    int bid = blockIdx.x;                        // 6400 = 4 ch-groups x 1600 tiles
    bid = (bid & 7) * 800 + (bid >> 3);          // XCD-contiguous chunks
    const int cg = bid / 1600;                   // 16-channel group
    const int tb = bid - cg * 1600;
    const int h = tb / 5;                        // input row (0..319)
    const int q = tb - 5 * h;                    // 128-col quarter (0..4)
    const int tid = threadIdx.x;
    const int ow = q * 128 + (tid & 127);
    const int oh = 2 * h + (tid >> 7);

    const int w = ow >> 1;
    const int ky = ow & 1, kx = oh & 1;
    const int p = h * W + w;
    float s_x = aff[p];
    float s_y = aff[HW + p];
    float th = (aff[2 * HW + p] - 1.f) * 1.0472f;
    float pnx = kx ? 0.5f : -0.5f;
    float pny = ky ? 0.5f : -0.5f;
    float px = pnx * s_x, py = pny * s_y;
    float st, ct;
    __sincosf(th, &st, &ct);
    float rx = px * ct - py * st;
    float ry = px * st + py * ct;
    float p_x = rx + 0.5f + (float)(h + 1);
    float p_y = ry + 0.5f + (float)(w + 1);
    float ltx = floorf(p_x), lty = floorf(p_y);
    float rbx = ltx + 1.f, rby = lty + 1.f;
    float ltxc = fminf(fmaxf(ltx, 0.f), 321.f);
    float ltyc = fminf(fmaxf(lty, 0.f), 321.f);
    float rbxc = fminf(fmaxf(rbx, 0.f), 321.f);
    float rbyc = fminf(fmaxf(rby, 0.f), 321.f);
    p_x = fminf(fmaxf(p_x, 0.f), 321.f);
    p_y = fminf(fmaxf(p_y, 0.f), 321.f);
    float gx0 = 1.f + ltxc - p_x;
    float gx1 = 1.f - (rbxc - p_x);
    float gy0 = 1.f + ltyc - p_y;
    float gy1 = 1.f - (rbyc - p_y);
    float g_lt = gx0 * gy0, g_rb = gx1 * gy1, g_lb = gx0 * gy1, g_rt = gx1 * gy0;
    int ix0 = reflmap((int)ltxc), ix1 = reflmap((int)rbxc);
    int iy0 = reflmap((int)ltyc), iy1 = reflmap((int)rbyc);

    // LDS word offsets within the staged [6][80-padded] window (in-range
    // proof: ix in [h-2, h+3], iy-colbase in [2, 70]).
    const int rowbase = h - 2;
    const int colbase = q * 64 - 4;
    const int o00 = (ix0 - rowbase) * 80 + (iy0 - colbase);
    const int o01 = (ix0 - rowbase) * 80 + (iy1 - colbase);
    const int o10 = (ix1 - rowbase) * 80 + (iy0 - colbase);
    const int o11 = (ix1 - rowbase) * 80 + (iy1 - colbase);
    const int obase = oh * 640 + ow;
    const int ch0 = cg * 16;

    // stage 16 ch x 6 rows x 18 float4 (72 valid words/row), zero-guarded
    for (int idx = tid; idx < 1728; idx += 256) {
        int ch = idx / 108;
        int rem = idx - ch * 108;
        int row = rem / 18;
        int g = rem - row * 18;
        int rv = rowbase + row;
        int cv = colbase + 4 * g;                // 4-aligned
        float4 v = make_float4(0.f, 0.f, 0.f, 0.f);
        if (rv >= 0 && rv < H && cv >= 0 && cv < W)
            v = *reinterpret_cast<const float4*>(x + (size_t)(ch0 + ch) * HW + rv * W + cv);
        *reinterpret_cast<float4*>(&tile[ch * 480 + row * 80 + 4 * g]) = v;
    }
    __syncthreads();

#pragma unroll
    for (int c = 0; c < 16; ++c) {
        const float* t = tile + c * 480;
        float v = g_lt * t[o00] + g_rb * t[o11] + g_lb * t[o01] + g_rt * t[o10];
        __builtin_nontemporal_store(v, outp + (size_t)(ch0 + c) * (640 * 640) + obase);
    }
}

// ---------------- launch ----------------------------------------------------
extern "C" void kernel_launch(void* const* d_in, const int* in_sizes, int n_in,
                              void* d_out, int out_size, void* d_ws, size_t ws_size,
                              hipStream_t stream) {
    const float* x       = (const float*)d_in[0];
    const float* query   = (const float*)d_in[1];
    const float* ref     = (const float*)d_in[2];
    const float* conv1_w = (const float*)d_in[3];
    const float* conv1_b = (const float*)d_in[4];
    const float* r1_w1   = (const float*)d_in[5];
    const float* r1_b1   = (const float*)d_in[6];
    const float* r1_w2   = (const float*)d_in[7];
    const float* r1_b2   = (const float*)d_in[8];
    const float* p1_w    = (const float*)d_in[9];
    const float* p1_b    = (const float*)d_in[10];
    const float* pr_w1   = (const float*)d_in[11];
    const float* pr_b1   = (const float*)d_in[12];
    const float* pr_w2   = (const float*)d_in[13];
    const float* pr_b2   = (const float*)d_in[14];
    const float* p2_w    = (const float*)d_in[15];
    const float* p2_b    = (const float*)d_in[16];

    float* outp = (float*)d_out;
    float* ws = (float*)d_ws;

    // ws (2.4 MB): fp32 qup + affine. d_out (104.8 MB) holds NHWC-f16
    // intermediates + repacked weights; all dead before sample_k rewrites it.
    float* qup    = ws;                        // 3*HW fp32
    float* affine = ws + 3 * HW;               // 3*HW fp32
    f16* feat = (f16*)outp;                    // [HW][64] (rf ch 0..31, qf 32..63)
    f16* Bt   = (f16*)(outp + 32 * HW);        // [2][HW][32] batch: 0=q, 1=ref
    f16* Ct   = (f16*)(outp + 64 * HW);        // [2][HW][32]
    f16* Dt   = (f16*)(outp + 96 * HW);        // [HW][32]
    f16* wrep = (f16*)(outp + 112 * HW);       // 90624 f16 repacked weights

    repack_k<<<45, 256, 0, stream>>>(r1_w1, r1_w2, pr_w1, pr_w2, p1_w, conv1_w, wrep);
    bicubic_k<<<1200, 256, 0, stream>>>(query, qup);

    // both heads, batch-2 (batch0 = qf from qup, batch1 = rf from ref)
    hconv_m<<<800, 256, 0, stream>>>(qup, ref, wrep + 88064, conv1_b, Bt);
    mconv_k<3, 32, 0, false><<<800, 256, 0, stream>>>(Bt, wrep,        r1_b1, nullptr, Ct,
                                                      32, 32 * HW, 0, 32 * HW, 0, 0);
    mconv_k<3, 32, 1, true ><<<800, 256, 0, stream>>>(Ct, wrep + 9216, r1_b2, Bt, feat,
                                                      64, 32 * HW, 32 * HW, 0, 32, -32);

    // fusion head (single batch)
    mconv_k<5, 64, 1, false><<<400, 256, 0, stream>>>(feat, wrep + 36864, p1_b, nullptr, Bt,
                                                      32, 0, 0, 0, 0, 0);
    mconv_k<3, 32, 0, false><<<400, 256, 0, stream>>>(Bt, wrep + 18432, pr_b1, nullptr, Ct,
                                                      32, 0, 0, 0, 0, 0);
    mconv_k<3, 32, 1, true ><<<400, 256, 0, stream>>>(Ct, wrep + 27648, pr_b2, Bt, Dt,
                                                      32, 0, 0, 0, 0, 0);

    affine_k<<<400, 256, 0, stream>>>(Dt, p2_w, p2_b, affine);

    sample_k<<<6400, 256, 0, stream>>>(x, affine, outp);
}

// Round 7
// 267.363 us; speedup vs baseline: 1.3257x; 1.0227x over previous
//
#include <hip/hip_runtime.h>

#define H 320
#define W 320
#define HW (H * W)          // 102400
#define CH 64

typedef _Float16 f16;
typedef _Float16 f16x8 __attribute__((ext_vector_type(8)));
typedef float f32x16 __attribute__((ext_vector_type(16)));

// ---------------- bicubic weight (A=-0.75) ----------------------------------
__device__ __forceinline__ float cubw(float t) {
    t = fabsf(t);
    if (t <= 1.f) return (1.25f * t - 2.25f) * t * t + 1.f;
    if (t < 2.f)  return -0.75f * (((t - 5.f) * t + 8.f) * t - 4.f);
    return 0.f;
}

// bicubic x2 sample of one query channel at output pixel (gy,gx), gy,gx in [0,320)
__device__ __forceinline__ float bicub(const float* __restrict__ qc, int gy, int gx) {
    float sy = gy * 0.5f - 0.25f;
    float sx = gx * 0.5f - 0.25f;
    int iy0 = (int)floorf(sy), ix0 = (int)floorf(sx);
    float o = 0.f;
#pragma unroll
    for (int b = 0; b < 4; b++) {
        int tx = ix0 - 1 + b;
        float wxv = cubw(sx - (float)tx);
        int txc = min(max(tx, 0), 159);
        float s = 0.f;
#pragma unroll
        for (int a = 0; a < 4; a++) {
            int ty = iy0 - 1 + a;
            float wyv = cubw(sy - (float)ty);
            int tyc = min(max(ty, 0), 159);
            s += wyv * qc[tyc * 160 + txc];
        }
        o += wxv * s;
    }
    return o;
}

// ---------------- weight repack: OIHW fp32 -> MFMA B-fragment order f16 -----
// Generic layers: per (kc, tap), lane l holds B[k=8*(l>>5)+i][oc=l&31].
// conv1 (li in [11008,11328)): tap-folded im2col K=80 (k = tap*3+ic, k>=75 -> 0).
__global__ __launch_bounds__(256) void repack_k(const float* __restrict__ w0, // r1_w1
                                                const float* __restrict__ w1, // r1_w2
                                                const float* __restrict__ w2, // pr_w1
                                                const float* __restrict__ w3, // pr_w2
                                                const float* __restrict__ w4, // p1_w
                                                const float* __restrict__ w5, // conv1_w
                                                f16* __restrict__ dst) {
    int li = blockIdx.x * 256 + threadIdx.x;
    if (li >= 11328) return;
    if (li >= 11008) {   // conv1: K=80 tap-folded, base 88064
        int rel = li - 11008;
        int kc = rel >> 6, l = rel & 63;
        int oc = l & 31, kh = l >> 5;
#pragma unroll
        for (int i = 0; i < 8; ++i) {
            int k = kc * 16 + kh * 8 + i;
            f16 v = (f16)0.f;
            if (k < 75) {
                int tap = k / 3, ic = k - 3 * tap;      // tap = ky*5+kx
                v = (f16)w5[(oc * 3 + ic) * 25 + tap];
            }
            dst[88064 + rel * 8 + i] = v;
        }
        return;
    }
    const float* src;
    int CIN, KS2, base, rel;
    if (li < 1152)       { src = w0; CIN = 32; KS2 = 9;  base = 0;     rel = li; }
    else if (li < 2304)  { src = w1; CIN = 32; KS2 = 9;  base = 9216;  rel = li - 1152; }
    else if (li < 3456)  { src = w2; CIN = 32; KS2 = 9;  base = 18432; rel = li - 2304; }
    else if (li < 4608)  { src = w3; CIN = 32; KS2 = 9;  base = 27648; rel = li - 3456; }
    else                 { src = w4; CIN = 64; KS2 = 25; base = 36864; rel = li - 4608; }
    int fi = rel >> 6, l = rel & 63;
    int kc = fi / KS2, t = fi - kc * KS2;
    int oc = l & 31, kh = l >> 5;
#pragma unroll
    for (int i = 0; i < 8; ++i) {
        int ic = kc * 16 + kh * 8 + i;
        dst[base + rel * 8 + i] = (f16)src[(oc * CIN + ic) * KS2 + t];
    }
}

// ---------------- conv1 via MFMA, tap-folded im2col (CIN=3, 5x5) ------------
// R7: bicubic fused into the stage for batch 0 (query upsample computed
// inline, fp32-identical to the old bicubic_k); batch 1 stages ref directly.
// 10 MFMA + 80 ds_read_b32/wave. Blocks 0..399 -> batch0, 400..799 -> batch1.
__global__ __launch_bounds__(256) void hconv_m(const float* __restrict__ query,
                                               const float* __restrict__ ref,
                                               const f16* __restrict__ wr5,
                                               const float* __restrict__ bias,
                                               f16* __restrict__ out) {
    __shared__ float tile[3][12][40];        // rows y0-2..y0+9, cols x0-2..x0+37
    const int b = blockIdx.x >= 400 ? 1 : 0;
    const int tb = blockIdx.x - b * 400;
    f16* o = out + (size_t)b * (32 * HW);
    const int x0 = (tb % 10) * 32, y0 = (tb / 10) * 8;
    const int tid = threadIdx.x;

    for (int idx = tid; idx < 1440; idx += 256) {
        int ic = idx / 480;
        int rem = idx - ic * 480;
        int r = rem / 40, c = rem - r * 40;
        int gy = y0 - 2 + r, gx = x0 - 2 + c;
        float v = 0.f;
        if (gy >= 0 && gy < H && gx >= 0 && gx < W)
            v = b ? ref[ic * HW + gy * W + gx]
                  : bicub(query + ic * 25600, gy, gx);
        tile[ic][r][c] = v;
    }
    __syncthreads();

    const int lane = tid & 63, wv = tid >> 6;
    const int R = lane & 31, hh = lane >> 5;

    f32x16 acc0, acc1;
#pragma unroll
    for (int j = 0; j < 16; ++j) { acc0[j] = 0.f; acc1[j] = 0.f; }

#pragma unroll
    for (int kc = 0; kc < 5; ++kc) {
        f16x8 B = *reinterpret_cast<const f16x8*>(wr5 + (kc * 64 + lane) * 8);
#pragma unroll
        for (int m = 0; m < 2; ++m) {
            f16x8 A;
#pragma unroll
            for (int i = 0; i < 8; ++i) {
                int k = kc * 16 + hh * 8 + i;
                float v = 0.f;
                if (k < 75) {
                    int tap = k / 3, ic = k - 3 * tap;
                    int dy = tap / 5, dx = tap - 5 * dy;
                    v = tile[ic][2 * wv + m + dy][R + dx];
                }
                A[i] = (f16)v;
            }
            if (m == 0) acc0 = __builtin_amdgcn_mfma_f32_32x32x16_f16(A, B, acc0, 0, 0, 0);
            else        acc1 = __builtin_amdgcn_mfma_f32_32x32x16_f16(A, B, acc1, 0, 0, 0);
        }
    }

    const float bv = bias[R];
#pragma unroll
    for (int m = 0; m < 2; ++m) {
        const int gy = y0 + 2 * wv + m;
        f32x16 a = m ? acc1 : acc0;
#pragma unroll
        for (int r = 0; r < 16; ++r) {
            int X = x0 + (r & 3) + 8 * (r >> 2) + 4 * hh;
            float v = a[r] + bv;
            v = (v > 0.f) ? v : 0.2f * v;              // lrelu
            o[(gy * W + X) * 32 + R] = (f16)v;
        }
    }
}

// ---------------- MFMA implicit-GEMM conv (NHWC f16 in/out, fp32 accum) -----
// Tap-decomposed GEMM on v_mfma_f32_32x32x16_f16 (verified R2). R2W = rows
// per wave: 2 = original (8-row tile, identical code path), 1 = 4-row tile
// (half LDS, 2x grid -> 8 blocks/CU for the occupancy-starved 3x3 layers).
// Batched: blocks-per-batch BPB = 800/R2W.
template <int KS, int CIN, int ACT, bool RES, int R2W>
__global__ __launch_bounds__(256) void mconv_k(const f16* __restrict__ in,
                                               const f16* __restrict__ wrep,
                                               const float* __restrict__ bias,
                                               const f16* __restrict__ res,
                                               f16* __restrict__ out,
                                               int OUTC, int inStr, int resStr,
                                               int outStr, int oc0Base, int oc0Step) {
    constexpr int PAD = KS / 2;
    constexpr int TROWS = 4 * R2W;
    constexpr int TY = TROWS + 2 * PAD;
    constexpr int TX = 32 + 2 * PAD;
    constexpr int NPX = TY * TX;
    constexpr int NU = CIN / 4;           // 8B units per pixel
    constexpr int UM = NU - 1;
    constexpr int KC = CIN / 16;
    constexpr int KS2 = KS * KS;
    constexpr int BPB = 800 / R2W;        // blocks per batch image

    __shared__ uint2 lds2[NPX * NU];

    const int b = blockIdx.x >= BPB ? 1 : 0;
    const int tb = blockIdx.x - b * BPB;
    in  += (size_t)b * inStr;
    res += (size_t)b * resStr;
    out += (size_t)b * outStr;
    const int oc0 = oc0Base + b * oc0Step;

    const int tid = threadIdx.x;
    const int bx = tb % 10;
    const int by = tb / 10;
    const int x0 = bx * 32, y0 = by * TROWS;

    // ---- stage NHWC tile (+halo), coalesced 8B loads, swizzled ds_writes ---
    {
        const int cu = tid & UM;
        constexpr int STEP = 256 / NU;
        for (int p = tid / NU; p < NPX; p += STEP) {
            int ly = p / TX, lx = p - ly * TX;
            int gy = y0 - PAD + ly, gx = x0 - PAD + lx;
            uint2 v; v.x = 0u; v.y = 0u;
            if (gy >= 0 && gy < H && gx >= 0 && gx < W)
                v = *reinterpret_cast<const uint2*>(in + (gy * W + gx) * CIN + cu * 4);
            lds2[p * NU + (cu ^ (p & UM))] = v;
        }
    }
    __syncthreads();

    const int lane = tid & 63;
    const int wv = tid >> 6;              // wave 0..3
    const int R = lane & 31;              // A pixel-x / B,D oc column
    const int hh = lane >> 5;

    f32x16 acc0, acc1;
#pragma unroll
    for (int j = 0; j < 16; ++j) { acc0[j] = 0.f; acc1[j] = 0.f; }

#pragma unroll
    for (int kc = 0; kc < KC; ++kc) {
#pragma unroll
        for (int t = 0; t < KS2; ++t) {
            const int dy = t / KS, dx = t - dy * KS;
            f16x8 B = *reinterpret_cast<const f16x8*>(
                wrep + ((kc * KS2 + t) * 64 + lane) * 8);
            const int u0 = (kc * 2 + hh) * 2;
            {   // m = 0
                int p = (R2W * wv + 0 + dy) * TX + R + dx;
                union { uint2 u[2]; f16x8 v; } A;
                A.u[0] = lds2[p * NU + ((u0)     ^ (p & UM))];
                A.u[1] = lds2[p * NU + ((u0 + 1) ^ (p & UM))];
                acc0 = __builtin_amdgcn_mfma_f32_32x32x16_f16(A.v, B, acc0, 0, 0, 0);
            }
            if constexpr (R2W == 2) {   // m = 1
                int p = (R2W * wv + 1 + dy) * TX + R + dx;
                union { uint2 u[2]; f16x8 v; } A;
                A.u[0] = lds2[p * NU + ((u0)     ^ (p & UM))];
                A.u[1] = lds2[p * NU + ((u0 + 1) ^ (p & UM))];
                acc1 = __builtin_amdgcn_mfma_f32_32x32x16_f16(A.v, B, acc1, 0, 0, 0);
            }
        }
    }

    // ---- epilogue: bias (+res) + activation, NHWC f16 stores ---------------
    const float bv = bias[R];
#pragma unroll
    for (int m = 0; m < R2W; ++m) {
        const int gy = y0 + R2W * wv + m;
        f32x16 a = m ? acc1 : acc0;
#pragma unroll
        for (int r = 0; r < 16; ++r) {
            int X = x0 + (r & 3) + 8 * (r >> 2) + 4 * hh;
            int pix = gy * W + X;
            float v = a[r] + bv;
            if constexpr (RES) v += (float)res[pix * 32 + R];
            if constexpr (ACT == 0) v = fmaxf(v, 0.f);
            else                    v = (v > 0.f) ? v : 0.2f * v;
            out[pix * OUTC + oc0 + R] = (f16)v;
        }
    }
}

// ---------------- 1x1 conv 32->3 (NHWC f16 in), +1, clip --------------------
__global__ __launch_bounds__(256) void affine_k(const f16* __restrict__ hid,
                                                const float* __restrict__ w,
                                                const float* __restrict__ b,
                                                float* __restrict__ outp) {
    int p = blockIdx.x * 256 + threadIdx.x;
    if (p >= HW) return;
    const f16x8* hv = reinterpret_cast<const f16x8*>(hid + p * 32);
    float a0 = 0.f, a1 = 0.f, a2 = 0.f;
#pragma unroll
    for (int cc = 0; cc < 4; ++cc) {
        f16x8 hb = hv[cc];
#pragma unroll
        for (int j = 0; j < 8; ++j) {
            float hval = (float)hb[j];
            int c = cc * 8 + j;
            a0 += hval * w[c];
            a1 += hval * w[32 + c];
            a2 += hval * w[64 + c];
        }
    }
    a0 = fminf(fmaxf(a0 + b[0] + 1.f, -3.f), 3.f);
    a1 = fminf(fmaxf(a1 + b[1] + 1.f, -3.f), 3.f);
    a2 = fminf(fmaxf(a2 + b[2] + 1.f, -3.f), 3.f);
    outp[p] = a0;
    outp[HW + p] = a1;
    outp[2 * HW + p] = a2;
}

// ---------------- deformable 2x2 bilinear sampling --------------------------
// R7: 8-channel groups (LDS 15.4 KB -> 8 blocks/CU = 32 waves, full occupancy)
// for latency hiding; grid 12800. XCD swizzle maps cg = XCD, so each XCD's L2
// holds only its 8 channels of x. Row stride 80 kept (bank-benign).
__device__ __forceinline__ int reflmap(int q) {
    int s = q - 1;
    if (s < 0) s = -s;
    else if (s > 319) s = 638 - s;
    return s;
}

__global__ __launch_bounds__(256) void sample_k(const float* __restrict__ x,
                                                const float* __restrict__ aff,
                                                float* __restrict__ outp) {
    __shared__ float tile[8 * 6 * 80];           // 15.4 KB
    int bid = blockIdx.x;                        // 12800 = 8 cg x 1600 tiles
    bid = (bid & 7) * 1600 + (bid >> 3);         // XCD-contiguous: cg == XCD
    const int cg = bid / 1600;                   // 8-channel group
    const int tb = bid - cg * 1600;
    const int h = tb / 5;                        // input row (0..319)
    const int q = tb - 5 * h;                    // 128-col quarter (0..4)
    const int tid = threadIdx.x;
    const int ow = q * 128 + (tid & 127);
    const int oh = 2 * h + (tid >> 7);

    const int w = ow >> 1;
    const int ky = ow & 1, kx = oh & 1;
    const int p = h * W + w;
    float s_x = aff[p];
    float s_y = aff[HW + p];
    float th = (aff[2 * HW + p] - 1.f) * 1.0472f;
    float pnx = kx ? 0.5f : -0.5f;
    float pny = ky ? 0.5f : -0.5f;
    float px = pnx * s_x, py = pny * s_y;
    float st, ct;
    __sincosf(th, &st, &ct);
    float rx = px * ct - py * st;
    float ry = px * st + py * ct;
    float p_x = rx + 0.5f + (float)(h + 1);
    float p_y = ry + 0.5f + (float)(w + 1);
    float ltx = floorf(p_x), lty = floorf(p_y);
    float rbx = ltx + 1.f, rby = lty + 1.f;
    float ltxc = fminf(fmaxf(ltx, 0.f), 321.f);
    float ltyc = fminf(fmaxf(lty, 0.f), 321.f);
    float rbxc = fminf(fmaxf(rbx, 0.f), 321.f);
    float rbyc = fminf(fmaxf(rby, 0.f), 321.f);
    p_x = fminf(fmaxf(p_x, 0.f), 321.f);
    p_y = fminf(fmaxf(p_y, 0.f), 321.f);
    float gx0 = 1.f + ltxc - p_x;
    float gx1 = 1.f - (rbxc - p_x);
    float gy0 = 1.f + ltyc - p_y;
    float gy1 = 1.f - (rbyc - p_y);
    float g_lt = gx0 * gy0, g_rb = gx1 * gy1, g_lb = gx0 * gy1, g_rt = gx1 * gy0;
    int ix0 = reflmap((int)ltxc), ix1 = reflmap((int)rbxc);
    int iy0 = reflmap((int)ltyc), iy1 = reflmap((int)rbyc);

    // LDS word offsets within the staged [6][80-padded] window (in-range
    // proof: ix in [h-2, h+3], iy-colbase in [2, 70]).
    const int rowbase = h - 2;
    const int colbase = q * 64 - 4;
    const int o00 = (ix0 - rowbase) * 80 + (iy0 - colbase);
    const int o01 = (ix0 - rowbase) * 80 + (iy1 - colbase);
    const int o10 = (ix1 - rowbase) * 80 + (iy0 - colbase);
    const int o11 = (ix1 - rowbase) * 80 + (iy1 - colbase);
    const int obase = oh * 640 + ow;
    const int ch0 = cg * 8;

    // stage 8 ch x 6 rows x 18 float4 (72 valid words/row), zero-guarded
    for (int idx = tid; idx < 864; idx += 256) {
        int ch = idx / 108;
        int rem = idx - ch * 108;
        int row = rem / 18;
        int g = rem - row * 18;
        int rv = rowbase + row;
        int cv = colbase + 4 * g;                // 4-aligned
        float4 v = make_float4(0.f, 0.f, 0.f, 0.f);
        if (rv >= 0 && rv < H && cv >= 0 && cv < W)
            v = *reinterpret_cast<const float4*>(x + (size_t)(ch0 + ch) * HW + rv * W + cv);
        *reinterpret_cast<float4*>(&tile[ch * 480 + row * 80 + 4 * g]) = v;
    }
    __syncthreads();

#pragma unroll
    for (int c = 0; c < 8; ++c) {
        const float* t = tile + c * 480;
        float v = g_lt * t[o00] + g_rb * t[o11] + g_lb * t[o01] + g_rt * t[o10];
        __builtin_nontemporal_store(v, outp + (size_t)(ch0 + c) * (640 * 640) + obase);
    }
}

// ---------------- launch ----------------------------------------------------
extern "C" void kernel_launch(void* const* d_in, const int* in_sizes, int n_in,
                              void* d_out, int out_size, void* d_ws, size_t ws_size,
                              hipStream_t stream) {
    const float* x       = (const float*)d_in[0];
    const float* query   = (const float*)d_in[1];
    const float* ref     = (const float*)d_in[2];
    const float* conv1_w = (const float*)d_in[3];
    const float* conv1_b = (const float*)d_in[4];
    const float* r1_w1   = (const float*)d_in[5];
    const float* r1_b1   = (const float*)d_in[6];
    const float* r1_w2   = (const float*)d_in[7];
    const float* r1_b2   = (const float*)d_in[8];
    const float* p1_w    = (const float*)d_in[9];
    const float* p1_b    = (const float*)d_in[10];
    const float* pr_w1   = (const float*)d_in[11];
    const float* pr_b1   = (const float*)d_in[12];
    const float* pr_w2   = (const float*)d_in[13];
    const float* pr_b2   = (const float*)d_in[14];
    const float* p2_w    = (const float*)d_in[15];
    const float* p2_b    = (const float*)d_in[16];

    float* outp = (float*)d_out;
    float* ws = (float*)d_ws;

    // ws (2.4 MB): fp32 affine. d_out (104.8 MB) holds NHWC-f16
    // intermediates + repacked weights; all dead before sample_k rewrites it.
    float* affine = ws;                        // 3*HW fp32
    f16* feat = (f16*)outp;                    // [HW][64] (rf ch 0..31, qf 32..63)
    f16* Bt   = (f16*)(outp + 32 * HW);        // [2][HW][32] batch: 0=q, 1=ref
    f16* Ct   = (f16*)(outp + 64 * HW);        // [2][HW][32]
    f16* Dt   = (f16*)(outp + 96 * HW);        // [HW][32]
    f16* wrep = (f16*)(outp + 112 * HW);       // 90624 f16 repacked weights

    repack_k<<<45, 256, 0, stream>>>(r1_w1, r1_w2, pr_w1, pr_w2, p1_w, conv1_w, wrep);

    // both heads, batch-2 (batch0 = qf from query via fused bicubic, batch1 = rf)
    hconv_m<<<800, 256, 0, stream>>>(query, ref, wrep + 88064, conv1_b, Bt);
    mconv_k<3, 32, 0, false, 1><<<1600, 256, 0, stream>>>(Bt, wrep,        r1_b1, nullptr, Ct,
                                                          32, 32 * HW, 0, 32 * HW, 0, 0);
    mconv_k<3, 32, 1, true , 1><<<1600, 256, 0, stream>>>(Ct, wrep + 9216, r1_b2, Bt, feat,
                                                          64, 32 * HW, 32 * HW, 0, 32, -32);

    // fusion head (single batch)
    mconv_k<5, 64, 1, false, 2><<<400, 256, 0, stream>>>(feat, wrep + 36864, p1_b, nullptr, Bt,
                                                         32, 0, 0, 0, 0, 0);
    mconv_k<3, 32, 0, false, 1><<<800, 256, 0, stream>>>(Bt, wrep + 18432, pr_b1, nullptr, Ct,
                                                         32, 0, 0, 0, 0, 0);
    mconv_k<3, 32, 1, true , 1><<<800, 256, 0, stream>>>(Ct, wrep + 27648, pr_b2, Bt, Dt,
                                                         32, 0, 0, 0, 0, 0);

    affine_k<<<400, 256, 0, stream>>>(Dt, p2_w, p2_b, affine);

    sample_k<<<12800, 256, 0, stream>>>(x, affine, outp);
}